// Round 1
// baseline (2358.459 us; speedup 1.0000x reference)
//
#include <hip/hip_runtime.h>
#include <hip/hip_bf16.h>

#define N_NODES 50000
#define N_EDGES 800000
#define N_B 128
#define H_DIM 256
#define H2_DIM 512
#define FIN_DIM 8
#define GF_DIM 85
#define LN_EPS 1e-5f

__device__ inline float relu_f(float x) { return x > 0.f ? x : 0.f; }

// LayerNorm stats across a 256-thread block (one value per thread)
__device__ inline void ln_stats_256(float v, float* sbuf, float& mean, float& rstd) {
    float s = v, s2 = v * v;
#pragma unroll
    for (int off = 32; off > 0; off >>= 1) {
        s += __shfl_down(s, off);
        s2 += __shfl_down(s2, off);
    }
    int t = threadIdx.x;
    if ((t & 63) == 0) { sbuf[t >> 6] = s; sbuf[4 + (t >> 6)] = s2; }
    __syncthreads();
    float ts = sbuf[0] + sbuf[1] + sbuf[2] + sbuf[3];
    float ts2 = sbuf[4] + sbuf[5] + sbuf[6] + sbuf[7];
    mean = ts * (1.f / H_DIM);
    float var = ts2 * (1.f / H_DIM) - mean * mean;
    rstd = rsqrtf(var + LN_EPS);
}

// ---------------- input projection: h = relu(LN(x @ W_in + b_in)) -------------
__global__ void k_input_proj(const float* __restrict__ x, const float* __restrict__ Wi,
                             const float* __restrict__ bi, const float* __restrict__ g,
                             const float* __restrict__ bb, float* __restrict__ h) {
    int n = blockIdx.x, t = threadIdx.x;
    __shared__ float xs[FIN_DIM];
    __shared__ float sbuf[8];
    if (t < FIN_DIM) xs[t] = x[n * FIN_DIM + t];
    __syncthreads();
    float acc = bi[t];
#pragma unroll
    for (int k = 0; k < FIN_DIM; ++k) acc = fmaf(xs[k], Wi[k * H_DIM + t], acc);
    float mean, rstd;
    ln_stats_256(acc, sbuf, mean, rstd);
    h[(size_t)n * H_DIM + t] = relu_f(g[t] * (acc - mean) * rstd + bb[t]);
}

// ---------------- CSR build ---------------------------------------------------
__global__ void k_hist(const int* __restrict__ ei, int* __restrict__ deg) {
    int e = blockIdx.x * 256 + threadIdx.x;
    atomicAdd(&deg[ei[N_EDGES + e]], 1);
}

__global__ void k_scan(const int* __restrict__ deg, int* __restrict__ row_start) {
    __shared__ int s[1024];
    __shared__ int carry;
    int t = threadIdx.x;
    if (t == 0) carry = 0;
    __syncthreads();
    for (int base = 0; base < N_NODES; base += 1024) {
        int i = base + t;
        int v = (i < N_NODES) ? deg[i] : 0;
        s[t] = v;
        __syncthreads();
        for (int off = 1; off < 1024; off <<= 1) {
            int xv = (t >= off) ? s[t - off] : 0;
            __syncthreads();
            s[t] += xv;
            __syncthreads();
        }
        int incl = s[t];
        if (i < N_NODES) row_start[i] = carry + incl - v;
        __syncthreads();
        if (t == 1023) carry += incl;
        __syncthreads();
    }
    if (t == 0) row_start[N_NODES] = N_EDGES;
}

__global__ void k_scatter(const int* __restrict__ ei, const float* __restrict__ ew,
                          const int* __restrict__ row_start, int* __restrict__ cursor,
                          int* __restrict__ csr_src, float* __restrict__ csr_w) {
    int e = blockIdx.x * 256 + threadIdx.x;
    int d = ei[N_EDGES + e];
    int p = atomicAdd(&cursor[d], 1);
    int i = row_start[d] + p;
    csr_src[i] = ei[e];
    csr_w[i] = ew[e];
}

__global__ void k_gcount(const int* __restrict__ batch, int* __restrict__ gcnt) {
    int n = blockIdx.x * 256 + threadIdx.x;
    if (n < N_NODES) atomicAdd(&gcnt[batch[n]], 1);
}

__global__ void k_gstart(const int* __restrict__ gcnt, int* __restrict__ gstart) {
    __shared__ int s[128];
    int t = threadIdx.x;
    int c = gcnt[t];
    s[t] = c;
    __syncthreads();
    for (int off = 1; off < 128; off <<= 1) {
        int xv = (t >= off) ? s[t - off] : 0;
        __syncthreads();
        s[t] += xv;
        __syncthreads();
    }
    gstart[t] = s[t] - c;  // exclusive
}

// ---------------- GIN aggregation: out0 = (2+eps)*h + sum_in w*h[src] ---------
__global__ void k_agg(const float* __restrict__ h, const int* __restrict__ row_start,
                      const int* __restrict__ csr_src, const float* __restrict__ csr_w,
                      const float* __restrict__ eps, int layer, float* __restrict__ A) {
    int n = blockIdx.x, t = threadIdx.x;
    __shared__ int s_src[256];
    __shared__ float s_w[256];
    int start = row_start[n], end = row_start[n + 1];
    float e2 = 2.0f + eps[layer];
    float hs = h[(size_t)n * H_DIM + t];
    float sum = 0.f;
    for (int e0 = start; e0 < end; e0 += 256) {
        int ne = end - e0; if (ne > 256) ne = 256;
        if (t < ne) { s_src[t] = csr_src[e0 + t]; s_w[t] = csr_w[e0 + t]; }
        __syncthreads();
        for (int j = 0; j < ne; ++j) sum = fmaf(s_w[j], h[(size_t)s_src[j] * H_DIM + t], sum);
        __syncthreads();
    }
    A[(size_t)n * H_DIM + t] = e2 * hs + sum;
}

// ---------------- GEMM1: C1 = relu(A[M,256] @ W[256,512] + b) -----------------
__global__ __launch_bounds__(256, 2) void k_gemm1(const float* __restrict__ A,
                                                  const float* __restrict__ W,
                                                  const float* __restrict__ bias,
                                                  float* __restrict__ C, int M) {
    __shared__ float As[128 * 36];
    __shared__ float Bs[32 * 132];
    const int t = threadIdx.x;
    const int tc = t & 15, tr = t >> 4;
    const int m0 = blockIdx.x * 128, n0 = blockIdx.y * 128;
    float acc[8][8];
#pragma unroll
    for (int r = 0; r < 8; ++r)
#pragma unroll
        for (int j = 0; j < 8; ++j) acc[r][j] = 0.f;

    for (int k0 = 0; k0 < H_DIM; k0 += 32) {
#pragma unroll
        for (int p = 0; p < 4; ++p) {
            int idx = t + 256 * p;
            int f4 = idx & 7, m = idx >> 3;
            int gm = m0 + m; gm = gm < M ? gm : M - 1;
            float4 v = *reinterpret_cast<const float4*>(&A[(size_t)gm * H_DIM + k0 + f4 * 4]);
            *reinterpret_cast<float4*>(&As[m * 36 + f4 * 4]) = v;
        }
#pragma unroll
        for (int p = 0; p < 4; ++p) {
            int idx = t + 256 * p;
            int c4 = idx & 31, kk = idx >> 5;
            float4 v = *reinterpret_cast<const float4*>(&W[(size_t)(k0 + kk) * H2_DIM + n0 + c4 * 4]);
            *reinterpret_cast<float4*>(&Bs[kk * 132 + c4 * 4]) = v;
        }
        __syncthreads();
#pragma unroll
        for (int kc = 0; kc < 8; ++kc) {
            float a[8][4]; float b[4][8];
#pragma unroll
            for (int r = 0; r < 8; ++r) {
                float4 v = *reinterpret_cast<const float4*>(&As[(tr + 16 * r) * 36 + kc * 4]);
                a[r][0] = v.x; a[r][1] = v.y; a[r][2] = v.z; a[r][3] = v.w;
            }
#pragma unroll
            for (int kk = 0; kk < 4; ++kk) {
                float4 v0 = *reinterpret_cast<const float4*>(&Bs[(kc * 4 + kk) * 132 + tc * 4]);
                float4 v1 = *reinterpret_cast<const float4*>(&Bs[(kc * 4 + kk) * 132 + 64 + tc * 4]);
                b[kk][0] = v0.x; b[kk][1] = v0.y; b[kk][2] = v0.z; b[kk][3] = v0.w;
                b[kk][4] = v1.x; b[kk][5] = v1.y; b[kk][6] = v1.z; b[kk][7] = v1.w;
            }
#pragma unroll
            for (int kk = 0; kk < 4; ++kk)
#pragma unroll
                for (int r = 0; r < 8; ++r)
#pragma unroll
                    for (int j = 0; j < 8; ++j)
                        acc[r][j] = fmaf(a[r][kk], b[kk][j], acc[r][j]);
        }
        __syncthreads();
    }
    float4 bi0 = *reinterpret_cast<const float4*>(&bias[n0 + tc * 4]);
    float4 bi1 = *reinterpret_cast<const float4*>(&bias[n0 + 64 + tc * 4]);
#pragma unroll
    for (int r = 0; r < 8; ++r) {
        int gm = m0 + tr + 16 * r;
        if (gm < M) {
            float4 o0, o1;
            o0.x = relu_f(acc[r][0] + bi0.x); o0.y = relu_f(acc[r][1] + bi0.y);
            o0.z = relu_f(acc[r][2] + bi0.z); o0.w = relu_f(acc[r][3] + bi0.w);
            o1.x = relu_f(acc[r][4] + bi1.x); o1.y = relu_f(acc[r][5] + bi1.y);
            o1.z = relu_f(acc[r][6] + bi1.z); o1.w = relu_f(acc[r][7] + bi1.w);
            *reinterpret_cast<float4*>(&C[(size_t)gm * H2_DIM + n0 + tc * 4]) = o0;
            *reinterpret_cast<float4*>(&C[(size_t)gm * H2_DIM + n0 + 64 + tc * 4]) = o1;
        }
    }
}

// ------- GEMM2 + LN + relu + residual: hout = relu(LN(C1@W2+b2)) + hres -------
__global__ __launch_bounds__(256, 2) void k_gemm2_ln(const float* __restrict__ C1,
                                                     const float* __restrict__ W,
                                                     const float* __restrict__ bias,
                                                     const float* __restrict__ lg,
                                                     const float* __restrict__ lb,
                                                     const float* __restrict__ hres,
                                                     float* __restrict__ hout, int M) {
    __shared__ float smem[64 * 36 + 32 * 260];  // 10624 floats
    float* As = smem;
    float* Bs = smem + 64 * 36;
    const int t = threadIdx.x;
    const int tc = t & 31, tr = t >> 5;
    const int m0 = blockIdx.x * 64;
    float acc[8][8];
#pragma unroll
    for (int r = 0; r < 8; ++r)
#pragma unroll
        for (int j = 0; j < 8; ++j) acc[r][j] = 0.f;

    for (int k0 = 0; k0 < H2_DIM; k0 += 32) {
#pragma unroll
        for (int p = 0; p < 2; ++p) {
            int idx = t + 256 * p;
            int f4 = idx & 7, m = idx >> 3;
            int gm = m0 + m; gm = gm < M ? gm : M - 1;
            float4 v = *reinterpret_cast<const float4*>(&C1[(size_t)gm * H2_DIM + k0 + f4 * 4]);
            *reinterpret_cast<float4*>(&As[m * 36 + f4 * 4]) = v;
        }
#pragma unroll
        for (int p = 0; p < 8; ++p) {
            int idx = t + 256 * p;
            int c4 = idx & 63, kk = idx >> 6;
            float4 v = *reinterpret_cast<const float4*>(&W[(size_t)(k0 + kk) * H_DIM + c4 * 4]);
            *reinterpret_cast<float4*>(&Bs[kk * 260 + c4 * 4]) = v;
        }
        __syncthreads();
#pragma unroll
        for (int kc = 0; kc < 8; ++kc) {
            float a[8][4]; float b[4][8];
#pragma unroll
            for (int r = 0; r < 8; ++r) {
                float4 v = *reinterpret_cast<const float4*>(&As[(tr + 8 * r) * 36 + kc * 4]);
                a[r][0] = v.x; a[r][1] = v.y; a[r][2] = v.z; a[r][3] = v.w;
            }
#pragma unroll
            for (int kk = 0; kk < 4; ++kk) {
                float4 v0 = *reinterpret_cast<const float4*>(&Bs[(kc * 4 + kk) * 260 + tc * 4]);
                float4 v1 = *reinterpret_cast<const float4*>(&Bs[(kc * 4 + kk) * 260 + 128 + tc * 4]);
                b[kk][0] = v0.x; b[kk][1] = v0.y; b[kk][2] = v0.z; b[kk][3] = v0.w;
                b[kk][4] = v1.x; b[kk][5] = v1.y; b[kk][6] = v1.z; b[kk][7] = v1.w;
            }
#pragma unroll
            for (int kk = 0; kk < 4; ++kk)
#pragma unroll
                for (int r = 0; r < 8; ++r)
#pragma unroll
                    for (int j = 0; j < 8; ++j)
                        acc[r][j] = fmaf(a[r][kk], b[kk][j], acc[r][j]);
        }
        __syncthreads();
    }
    // bias
    float4 bi0 = *reinterpret_cast<const float4*>(&bias[tc * 4]);
    float4 bi1 = *reinterpret_cast<const float4*>(&bias[128 + tc * 4]);
#pragma unroll
    for (int r = 0; r < 8; ++r) {
        acc[r][0] += bi0.x; acc[r][1] += bi0.y; acc[r][2] += bi0.z; acc[r][3] += bi0.w;
        acc[r][4] += bi1.x; acc[r][5] += bi1.y; acc[r][6] += bi1.z; acc[r][7] += bi1.w;
    }
    // LN reduction (reuse smem; previous loop ended with __syncthreads)
    float* red_s = smem;           // 64*33
    float* red_s2 = smem + 2112;   // 64*33
    float* meanb = smem + 4224;    // 64
    float* rstdb = smem + 4288;    // 64
#pragma unroll
    for (int r = 0; r < 8; ++r) {
        float s = 0.f, s2 = 0.f;
#pragma unroll
        for (int j = 0; j < 8; ++j) { float v = acc[r][j]; s += v; s2 += v * v; }
        red_s[(tr + 8 * r) * 33 + tc] = s;
        red_s2[(tr + 8 * r) * 33 + tc] = s2;
    }
    __syncthreads();
    if (t < 64) {
        float s = 0.f, s2 = 0.f;
        for (int i = 0; i < 32; ++i) { s += red_s[t * 33 + i]; s2 += red_s2[t * 33 + i]; }
        float m = s * (1.f / 256.f);
        float var = s2 * (1.f / 256.f) - m * m;
        meanb[t] = m;
        rstdb[t] = rsqrtf(var + LN_EPS);
    }
    __syncthreads();
    float4 g0 = *reinterpret_cast<const float4*>(&lg[tc * 4]);
    float4 g1 = *reinterpret_cast<const float4*>(&lg[128 + tc * 4]);
    float4 lb0 = *reinterpret_cast<const float4*>(&lb[tc * 4]);
    float4 lb1 = *reinterpret_cast<const float4*>(&lb[128 + tc * 4]);
#pragma unroll
    for (int r = 0; r < 8; ++r) {
        int row = tr + 8 * r, gm = m0 + row;
        if (gm < M) {
            float m = meanb[row], rs = rstdb[row];
            float4 h0 = *reinterpret_cast<const float4*>(&hres[(size_t)gm * H_DIM + tc * 4]);
            float4 h1 = *reinterpret_cast<const float4*>(&hres[(size_t)gm * H_DIM + 128 + tc * 4]);
            float4 o0, o1;
            o0.x = relu_f(g0.x * (acc[r][0] - m) * rs + lb0.x) + h0.x;
            o0.y = relu_f(g0.y * (acc[r][1] - m) * rs + lb0.y) + h0.y;
            o0.z = relu_f(g0.z * (acc[r][2] - m) * rs + lb0.z) + h0.z;
            o0.w = relu_f(g0.w * (acc[r][3] - m) * rs + lb0.w) + h0.w;
            o1.x = relu_f(g1.x * (acc[r][4] - m) * rs + lb1.x) + h1.x;
            o1.y = relu_f(g1.y * (acc[r][5] - m) * rs + lb1.y) + h1.y;
            o1.z = relu_f(g1.z * (acc[r][6] - m) * rs + lb1.z) + h1.z;
            o1.w = relu_f(g1.w * (acc[r][7] - m) * rs + lb1.w) + h1.w;
            *reinterpret_cast<float4*>(&hout[(size_t)gm * H_DIM + tc * 4]) = o0;
            *reinterpret_cast<float4*>(&hout[(size_t)gm * H_DIM + 128 + tc * 4]) = o1;
        }
    }
}

// ---------------- pooling (mean + max per graph) ------------------------------
__global__ void k_pool(const float* __restrict__ h, const int* __restrict__ gstart,
                       const int* __restrict__ gcnt, float* __restrict__ g) {
    int b = blockIdx.x, t = threadIdx.x;
    int st = gstart[b], cnt = gcnt[b];
    float s = 0.f, mx = -3.4e38f;
    for (int i = 0; i < cnt; ++i) {
        float v = h[(size_t)(st + i) * H_DIM + t];
        s += v; mx = fmaxf(mx, v);
    }
    float mean = cnt > 0 ? s / (float)cnt : 0.f;
    if (cnt == 0) mx = 0.f;
    g[b * 640 + t] = mean;
    g[b * 640 + 256 + t] = mx;
}

// ---------------- gene projection --------------------------------------------
__global__ void k_gene(const float* __restrict__ gf, const float* __restrict__ Wg1,
                       const float* __restrict__ bg1, const float* __restrict__ lg,
                       const float* __restrict__ lb, const float* __restrict__ Wg2,
                       const float* __restrict__ bg2, float* __restrict__ g) {
    int b = blockIdx.x, t = threadIdx.x;
    __shared__ float xs[GF_DIM];
    __shared__ float sbuf[8];
    __shared__ float s1[H_DIM];
    if (t < GF_DIM) xs[t] = gf[b * GF_DIM + t];
    __syncthreads();
    float acc = bg1[t];
    for (int k = 0; k < GF_DIM; ++k) acc = fmaf(xs[k], Wg1[k * H_DIM + t], acc);
    float mean, rstd;
    ln_stats_256(acc, sbuf, mean, rstd);
    s1[t] = relu_f(lg[t] * (acc - mean) * rstd + lb[t]);
    __syncthreads();
    if (t < 128) {
        float a2 = bg2[t];
        for (int k = 0; k < H_DIM; ++k) a2 = fmaf(s1[k], Wg2[k * 128 + t], a2);
        g[b * 640 + 512 + t] = relu_f(a2);
    }
}

// ---------------- classifier --------------------------------------------------
__global__ void k_cls(const float* __restrict__ g, const float* __restrict__ Wc1,
                      const float* __restrict__ bc1, const float* __restrict__ Wc2,
                      const float* __restrict__ bc2, const float* __restrict__ Wc3,
                      const float* __restrict__ bc3, float* __restrict__ out) {
    int b = blockIdx.x, t = threadIdx.x;
    __shared__ float gg[640];
    __shared__ float s1[256];
    __shared__ float s2[128];
    gg[t] = g[b * 640 + t];
    gg[t + 256] = g[b * 640 + 256 + t];
    if (t < 128) gg[t + 512] = g[b * 640 + 512 + t];
    __syncthreads();
    float a = bc1[t];
    for (int k = 0; k < 640; ++k) a = fmaf(gg[k], Wc1[k * 256 + t], a);
    s1[t] = relu_f(a);
    __syncthreads();
    if (t < 128) {
        float a2 = bc2[t];
        for (int k = 0; k < 256; ++k) a2 = fmaf(s1[k], Wc2[k * 128 + t], a2);
        s2[t] = relu_f(a2);
    }
    __syncthreads();
    if (t < 2) {
        float a3 = bc3[t];
        for (int k = 0; k < 128; ++k) a3 = fmaf(s2[k], Wc3[k * 2 + t], a3);
        out[b * 2 + t] = a3;
    }
}

extern "C" void kernel_launch(void* const* d_in, const int* in_sizes, int n_in,
                              void* d_out, int out_size, void* d_ws, size_t ws_size,
                              hipStream_t stream) {
    const float* x = (const float*)d_in[0];
    const int* ei = (const int*)d_in[1];
    const float* ew = (const float*)d_in[2];
    const int* batch = (const int*)d_in[3];
    const float* gf = (const float*)d_in[4];
    const float* W_in = (const float*)d_in[5];
    const float* b_in = (const float*)d_in[6];
    const float* ln_in_g = (const float*)d_in[7];
    const float* ln_in_b = (const float*)d_in[8];
    const float* eps = (const float*)d_in[9];
    const float* W1 = (const float*)d_in[10];
    const float* b1 = (const float*)d_in[11];
    const float* W2 = (const float*)d_in[12];
    const float* b2 = (const float*)d_in[13];
    const float* ln_g = (const float*)d_in[14];
    const float* ln_b = (const float*)d_in[15];
    const float* Wg1 = (const float*)d_in[16];
    const float* bg1 = (const float*)d_in[17];
    const float* lng_g = (const float*)d_in[18];
    const float* lng_b = (const float*)d_in[19];
    const float* Wg2 = (const float*)d_in[20];
    const float* bg2 = (const float*)d_in[21];
    const float* Wc1 = (const float*)d_in[22];
    const float* bc1 = (const float*)d_in[23];
    const float* Wc2 = (const float*)d_in[24];
    const float* bc2 = (const float*)d_in[25];
    const float* Wc3 = (const float*)d_in[26];
    const float* bc3 = (const float*)d_in[27];
    float* out = (float*)d_out;

    char* ws = (char*)d_ws;
    size_t off = 0;
    auto alloc = [&](size_t bytes) -> char* {
        char* p = ws + off;
        off += (bytes + 255) & ~(size_t)255;
        return p;
    };
    float* H0 = (float*)alloc((size_t)N_NODES * H_DIM * 4);
    float* H1 = (float*)alloc((size_t)N_NODES * H_DIM * 4);
    float* C1 = (float*)alloc((size_t)N_NODES * H2_DIM * 4);
    int* deg = (int*)alloc(N_NODES * 4);
    int* cursor = (int*)alloc(N_NODES * 4);
    int* gcnt = (int*)alloc(N_B * 4);
    int* row_start = (int*)alloc((N_NODES + 1) * 4);
    int* gstart = (int*)alloc(N_B * 4);
    int* csr_src = (int*)alloc(N_EDGES * 4);
    float* csr_w = (float*)alloc(N_EDGES * 4);
    float* gbuf = (float*)alloc(N_B * 640 * 4);
    (void)ws_size; (void)in_sizes; (void)n_in; (void)out_size;

    // zero deg + cursor + gcnt (contiguous allocations)
    hipMemsetAsync(deg, 0, (size_t)((char*)row_start - (char*)deg), stream);

    k_input_proj<<<N_NODES, 256, 0, stream>>>(x, W_in, b_in, ln_in_g, ln_in_b, H0);
    k_hist<<<N_EDGES / 256, 256, 0, stream>>>(ei, deg);
    k_scan<<<1, 1024, 0, stream>>>(deg, row_start);
    k_scatter<<<N_EDGES / 256, 256, 0, stream>>>(ei, ew, row_start, cursor, csr_src, csr_w);
    k_gcount<<<(N_NODES + 255) / 256, 256, 0, stream>>>(batch, gcnt);
    k_gstart<<<1, 128, 0, stream>>>(gcnt, gstart);

    float* hc = H0;
    float* hn = H1;
    for (int l = 0; l < 4; ++l) {
        k_agg<<<N_NODES, 256, 0, stream>>>(hc, row_start, csr_src, csr_w, eps, l, hn);
        k_gemm1<<<dim3((N_NODES + 127) / 128, 4), 256, 0, stream>>>(
            hn, W1 + (size_t)l * H_DIM * H2_DIM, b1 + (size_t)l * H2_DIM, C1, N_NODES);
        k_gemm2_ln<<<(N_NODES + 63) / 64, 256, 0, stream>>>(
            C1, W2 + (size_t)l * H2_DIM * H_DIM, b2 + (size_t)l * H_DIM,
            ln_g + (size_t)l * H_DIM, ln_b + (size_t)l * H_DIM, hc, hn, N_NODES);
        float* tmp = hc; hc = hn; hn = tmp;
    }

    k_pool<<<N_B, 256, 0, stream>>>(hc, gstart, gcnt, gbuf);
    k_gene<<<N_B, 256, 0, stream>>>(gf, Wg1, bg1, lng_g, lng_b, Wg2, bg2, gbuf);
    k_cls<<<N_B, 256, 0, stream>>>(gbuf, Wc1, bc1, Wc2, bc2, Wc3, bc3, out);
}

// Round 2
// 1605.379 us; speedup vs baseline: 1.4691x; 1.4691x over previous
//
#include <hip/hip_runtime.h>
#include <hip/hip_bf16.h>

#define N_NODES 50000
#define MP 50048            // padded row count (multiple of 128)
#define N_EDGES 800000
#define N_B 128
#define H_DIM 256
#define H2_DIM 512
#define FIN_DIM 8
#define GF_DIM 85
#define LN_EPS 1e-5f

typedef unsigned short u16;
typedef unsigned int u32;
typedef __attribute__((ext_vector_type(8))) short bf16x8;
typedef __attribute__((ext_vector_type(4))) float f32x4;

__device__ inline float relu_f(float x) { return x > 0.f ? x : 0.f; }

__device__ inline u16 f2bf(float x) {  // RNE float -> bf16 bits
    u32 u = __float_as_uint(x);
    u32 r = u + 0x7fffu + ((u >> 16) & 1u);
    return (u16)(r >> 16);
}
__device__ inline float bf2f(u16 b) { return __uint_as_float(((u32)b) << 16); }

#define GLOAD16(gp, lp) __builtin_amdgcn_global_load_lds( \
    (const __attribute__((address_space(1))) void*)(gp),  \
    (__attribute__((address_space(3))) void*)(lp), 16, 0, 0)

// LayerNorm stats across a 256-thread block (one value per thread)
__device__ inline void ln_stats_256(float v, float* sbuf, float& mean, float& rstd) {
    float s = v, s2 = v * v;
#pragma unroll
    for (int off = 32; off > 0; off >>= 1) {
        s += __shfl_down(s, off);
        s2 += __shfl_down(s2, off);
    }
    int t = threadIdx.x;
    if ((t & 63) == 0) { sbuf[t >> 6] = s; sbuf[4 + (t >> 6)] = s2; }
    __syncthreads();
    float ts = sbuf[0] + sbuf[1] + sbuf[2] + sbuf[3];
    float ts2 = sbuf[4] + sbuf[5] + sbuf[6] + sbuf[7];
    mean = ts * (1.f / H_DIM);
    float var = ts2 * (1.f / H_DIM) - mean * mean;
    rstd = rsqrtf(var + LN_EPS);
}

// ---------------- input projection: h = relu(LN(x @ W_in + b_in)) -------------
__global__ void k_input_proj(const float* __restrict__ x, const float* __restrict__ Wi,
                             const float* __restrict__ bi, const float* __restrict__ g,
                             const float* __restrict__ bb, float* __restrict__ h) {
    int n = blockIdx.x, t = threadIdx.x;
    __shared__ float xs[FIN_DIM];
    __shared__ float sbuf[8];
    if (t < FIN_DIM) xs[t] = x[n * FIN_DIM + t];
    __syncthreads();
    float acc = bi[t];
#pragma unroll
    for (int k = 0; k < FIN_DIM; ++k) acc = fmaf(xs[k], Wi[k * H_DIM + t], acc);
    float mean, rstd;
    ln_stats_256(acc, sbuf, mean, rstd);
    h[(size_t)n * H_DIM + t] = relu_f(g[t] * (acc - mean) * rstd + bb[t]);
}

// ---------------- CSR build ---------------------------------------------------
__global__ void k_hist(const int* __restrict__ ei, int* __restrict__ deg) {
    int e = blockIdx.x * 256 + threadIdx.x;
    atomicAdd(&deg[ei[N_EDGES + e]], 1);
}

__global__ void k_scan(const int* __restrict__ deg, int* __restrict__ row_start) {
    __shared__ int s[1024];
    __shared__ int carry;
    int t = threadIdx.x;
    if (t == 0) carry = 0;
    __syncthreads();
    for (int base = 0; base < N_NODES; base += 1024) {
        int i = base + t;
        int v = (i < N_NODES) ? deg[i] : 0;
        s[t] = v;
        __syncthreads();
        for (int off = 1; off < 1024; off <<= 1) {
            int xv = (t >= off) ? s[t - off] : 0;
            __syncthreads();
            s[t] += xv;
            __syncthreads();
        }
        int incl = s[t];
        if (i < N_NODES) row_start[i] = carry + incl - v;
        __syncthreads();
        if (t == 1023) carry += incl;
        __syncthreads();
    }
    if (t == 0) row_start[N_NODES] = N_EDGES;
}

__global__ void k_scatter(const int* __restrict__ ei, const float* __restrict__ ew,
                          const int* __restrict__ row_start, int* __restrict__ cursor,
                          int* __restrict__ csr_src, float* __restrict__ csr_w) {
    int e = blockIdx.x * 256 + threadIdx.x;
    int d = ei[N_EDGES + e];
    int p = atomicAdd(&cursor[d], 1);
    int i = row_start[d] + p;
    csr_src[i] = ei[e];
    csr_w[i] = ew[e];
}

__global__ void k_gcount(const int* __restrict__ batch, int* __restrict__ gcnt) {
    int n = blockIdx.x * 256 + threadIdx.x;
    if (n < N_NODES) atomicAdd(&gcnt[batch[n]], 1);
}

__global__ void k_gstart(const int* __restrict__ gcnt, int* __restrict__ gstart) {
    __shared__ int s[128];
    int t = threadIdx.x;
    int c = gcnt[t];
    s[t] = c;
    __syncthreads();
    for (int off = 1; off < 128; off <<= 1) {
        int xv = (t >= off) ? s[t - off] : 0;
        __syncthreads();
        s[t] += xv;
        __syncthreads();
    }
    gstart[t] = s[t] - c;  // exclusive
}

// -------- GIN aggregation: A = (2+eps)*h + sum_in w*h[src], split-bf16 out ----
__global__ void k_agg(const float* __restrict__ h, const int* __restrict__ row_start,
                      const int* __restrict__ csr_src, const float* __restrict__ csr_w,
                      const float* __restrict__ eps, int layer,
                      u16* __restrict__ Ah, u16* __restrict__ Al) {
    int n = blockIdx.x, t = threadIdx.x;
    __shared__ int s_src[256];
    __shared__ float s_w[256];
    int start = row_start[n], end = row_start[n + 1];
    float e2 = 2.0f + eps[layer];
    float hs = h[(size_t)n * H_DIM + t];
    float sum = 0.f;
    for (int e0 = start; e0 < end; e0 += 256) {
        int ne = end - e0; if (ne > 256) ne = 256;
        if (t < ne) { s_src[t] = csr_src[e0 + t]; s_w[t] = csr_w[e0 + t]; }
        __syncthreads();
        for (int j = 0; j < ne; ++j) sum = fmaf(s_w[j], h[(size_t)s_src[j] * H_DIM + t], sum);
        __syncthreads();
    }
    float v = e2 * hs + sum;
    u16 hh = f2bf(v);
    Ah[(size_t)n * H_DIM + t] = hh;
    Al[(size_t)n * H_DIM + t] = f2bf(v - bf2f(hh));
}

// ------------- weight transpose + split: W[4][R][C] -> T[4][C][R] -------------
__global__ void k_wprep(const float* __restrict__ W, u16* __restrict__ Th,
                        u16* __restrict__ Tl, int R, int C) {
    int idx = blockIdx.x * 256 + threadIdx.x;
    int per = R * C;
    int l = idx / per;
    int rem = idx - l * per;
    int r = rem / C;
    int c = rem - r * C;
    float v = W[idx];
    u16 hh = f2bf(v);
    size_t o = (size_t)l * per + (size_t)c * R + r;
    Th[o] = hh;
    Tl[o] = f2bf(v - bf2f(hh));
}

// ---- MFMA GEMM1: C1 = relu(A[MP,256] @ W1[256,512] + b), split-bf16 io -------
// A split (Ah,Al) [MP][256]; W1T split [512][256]; out C1 split [MP][512]
__global__ __launch_bounds__(256, 2) void k_mgemm1(
    const u16* __restrict__ Ah, const u16* __restrict__ Al,
    const u16* __restrict__ Wh, const u16* __restrict__ Wl,
    const float* __restrict__ bias, u16* __restrict__ Ch, u16* __restrict__ Cl) {
    __shared__ __align__(16) u16 sA[2][128 * 32];
    __shared__ __align__(16) u16 sB[2][128 * 32];
    const int t = threadIdx.x;
    const int wv = t >> 6, lane = t & 63;
    const int fr = lane & 15, kg = lane >> 4;
    const int m0 = blockIdx.x * 128, n0 = blockIdx.y * 128;
    const int wm = (wv >> 1) * 64, wn = (wv & 1) * 64;

    f32x4 acc[4][4];
#pragma unroll
    for (int i = 0; i < 4; ++i)
#pragma unroll
        for (int j = 0; j < 4; ++j) acc[i][j] = (f32x4){0.f, 0.f, 0.f, 0.f};

    for (int k0 = 0; k0 < 256; k0 += 32) {
#pragma unroll
        for (int is = 0; is < 2; ++is) {
            int chunk = wv * 128 + is * 64 + lane;
            int r = chunk >> 2, p = chunk & 3;
            size_t ea = (size_t)(m0 + r) * 256 + k0 + p * 8;
            size_t eb = (size_t)(n0 + r) * 256 + k0 + p * 8;
            int lbase = (wv * 128 + is * 64) * 8;
            GLOAD16(Ah + ea, &sA[0][lbase]);
            GLOAD16(Al + ea, &sA[1][lbase]);
            GLOAD16(Wh + eb, &sB[0][lbase]);
            GLOAD16(Wl + eb, &sB[1][lbase]);
        }
        __syncthreads();
        bf16x8 fa[4][2], fb[4][2];
#pragma unroll
        for (int mf = 0; mf < 4; ++mf) {
            int off = (wm + mf * 16 + fr) * 32 + kg * 8;
            fa[mf][0] = *(const bf16x8*)&sA[0][off];
            fa[mf][1] = *(const bf16x8*)&sA[1][off];
        }
#pragma unroll
        for (int nf = 0; nf < 4; ++nf) {
            int off = (wn + nf * 16 + fr) * 32 + kg * 8;
            fb[nf][0] = *(const bf16x8*)&sB[0][off];
            fb[nf][1] = *(const bf16x8*)&sB[1][off];
        }
#pragma unroll
        for (int mf = 0; mf < 4; ++mf)
#pragma unroll
            for (int nf = 0; nf < 4; ++nf) {
                acc[mf][nf] = __builtin_amdgcn_mfma_f32_16x16x32_bf16(fa[mf][0], fb[nf][0], acc[mf][nf], 0, 0, 0);
                acc[mf][nf] = __builtin_amdgcn_mfma_f32_16x16x32_bf16(fa[mf][0], fb[nf][1], acc[mf][nf], 0, 0, 0);
                acc[mf][nf] = __builtin_amdgcn_mfma_f32_16x16x32_bf16(fa[mf][1], fb[nf][0], acc[mf][nf], 0, 0, 0);
            }
        __syncthreads();
    }
#pragma unroll
    for (int nf = 0; nf < 4; ++nf) {
        int col = n0 + wn + nf * 16 + fr;
        float bi = bias[col];
#pragma unroll
        for (int mf = 0; mf < 4; ++mf)
#pragma unroll
            for (int j = 0; j < 4; ++j) {
                int grow = m0 + wm + mf * 16 + kg * 4 + j;
                float v = relu_f(acc[mf][nf][j] + bi);
                u16 hh = f2bf(v);
                u16 ll = f2bf(v - bf2f(hh));
                size_t o = (size_t)grow * 512 + col;
                Ch[o] = hh;
                Cl[o] = ll;
            }
    }
}

// -- MFMA GEMM2 + LN + relu + residual: hout = relu(LN(C1@W2+b2)) + hres -------
// C1 split [MP][512]; W2T split [256][512]; hres/hout fp32 [MP][256]
__global__ __launch_bounds__(256, 2) void k_mgemm2(
    const u16* __restrict__ Ah, const u16* __restrict__ Al,
    const u16* __restrict__ Wh, const u16* __restrict__ Wl,
    const float* __restrict__ bias, const float* __restrict__ lg,
    const float* __restrict__ lbv, const float* __restrict__ hres,
    float* __restrict__ hout) {
    __shared__ __align__(16) u16 sA[2][64 * 32];
    __shared__ __align__(16) u16 sB[2][256 * 32];
    __shared__ float lnS[64][4], lnS2[64][4];
    __shared__ float lnm[64], lnr[64];
    const int t = threadIdx.x;
    const int wv = t >> 6, lane = t & 63;
    const int fr = lane & 15, kg = lane >> 4;
    const int m0 = blockIdx.x * 64;

    f32x4 acc[4][4];
#pragma unroll
    for (int i = 0; i < 4; ++i)
#pragma unroll
        for (int j = 0; j < 4; ++j) acc[i][j] = (f32x4){0.f, 0.f, 0.f, 0.f};

    for (int k0 = 0; k0 < 512; k0 += 32) {
        {
            int r = t >> 2, p = t & 3;
            size_t ea = (size_t)(m0 + r) * 512 + k0 + p * 8;
            int lbase = (wv * 64) * 8;
            GLOAD16(Ah + ea, &sA[0][lbase]);
            GLOAD16(Al + ea, &sA[1][lbase]);
        }
#pragma unroll
        for (int is = 0; is < 4; ++is) {
            int chunk = is * 256 + t;
            int r = chunk >> 2, p = chunk & 3;
            size_t eb = (size_t)r * 512 + k0 + p * 8;
            int lbase = (is * 256 + wv * 64) * 8;
            GLOAD16(Wh + eb, &sB[0][lbase]);
            GLOAD16(Wl + eb, &sB[1][lbase]);
        }
        __syncthreads();
        bf16x8 fa[4][2], fb[4][2];
#pragma unroll
        for (int mf = 0; mf < 4; ++mf) {
            int off = (mf * 16 + fr) * 32 + kg * 8;
            fa[mf][0] = *(const bf16x8*)&sA[0][off];
            fa[mf][1] = *(const bf16x8*)&sA[1][off];
        }
#pragma unroll
        for (int nf = 0; nf < 4; ++nf) {
            int off = (wv * 64 + nf * 16 + fr) * 32 + kg * 8;
            fb[nf][0] = *(const bf16x8*)&sB[0][off];
            fb[nf][1] = *(const bf16x8*)&sB[1][off];
        }
#pragma unroll
        for (int mf = 0; mf < 4; ++mf)
#pragma unroll
            for (int nf = 0; nf < 4; ++nf) {
                acc[mf][nf] = __builtin_amdgcn_mfma_f32_16x16x32_bf16(fa[mf][0], fb[nf][0], acc[mf][nf], 0, 0, 0);
                acc[mf][nf] = __builtin_amdgcn_mfma_f32_16x16x32_bf16(fa[mf][0], fb[nf][1], acc[mf][nf], 0, 0, 0);
                acc[mf][nf] = __builtin_amdgcn_mfma_f32_16x16x32_bf16(fa[mf][1], fb[nf][0], acc[mf][nf], 0, 0, 0);
            }
        __syncthreads();
    }
    // bias (before LN stats)
    float bcol[4];
#pragma unroll
    for (int nf = 0; nf < 4; ++nf) bcol[nf] = bias[wv * 64 + nf * 16 + fr];
#pragma unroll
    for (int mf = 0; mf < 4; ++mf)
#pragma unroll
        for (int nf = 0; nf < 4; ++nf)
#pragma unroll
            for (int j = 0; j < 4; ++j) acc[mf][nf][j] += bcol[nf];
    // LN row stats: reduce over 4 nf per lane, then 16 fr-lanes, then 4 waves
#pragma unroll
    for (int mf = 0; mf < 4; ++mf)
#pragma unroll
        for (int j = 0; j < 4; ++j) {
            float s = acc[mf][0][j] + acc[mf][1][j] + acc[mf][2][j] + acc[mf][3][j];
            float s2 = acc[mf][0][j] * acc[mf][0][j] + acc[mf][1][j] * acc[mf][1][j] +
                       acc[mf][2][j] * acc[mf][2][j] + acc[mf][3][j] * acc[mf][3][j];
#pragma unroll
            for (int off = 1; off < 16; off <<= 1) {
                s += __shfl_xor(s, off);
                s2 += __shfl_xor(s2, off);
            }
            if (fr == 0) {
                int row = mf * 16 + kg * 4 + j;
                lnS[row][wv] = s;
                lnS2[row][wv] = s2;
            }
        }
    __syncthreads();
    if (t < 64) {
        float s = lnS[t][0] + lnS[t][1] + lnS[t][2] + lnS[t][3];
        float s2 = lnS2[t][0] + lnS2[t][1] + lnS2[t][2] + lnS2[t][3];
        float m = s * (1.f / 256.f);
        float var = s2 * (1.f / 256.f) - m * m;
        lnm[t] = m;
        lnr[t] = rsqrtf(var + LN_EPS);
    }
    __syncthreads();
    float gg[4], bb[4];
#pragma unroll
    for (int nf = 0; nf < 4; ++nf) {
        int col = wv * 64 + nf * 16 + fr;
        gg[nf] = lg[col];
        bb[nf] = lbv[col];
    }
#pragma unroll
    for (int mf = 0; mf < 4; ++mf)
#pragma unroll
        for (int j = 0; j < 4; ++j) {
            int row = mf * 16 + kg * 4 + j;
            int grow = m0 + row;
            float m = lnm[row], rs = lnr[row];
#pragma unroll
            for (int nf = 0; nf < 4; ++nf) {
                int col = wv * 64 + nf * 16 + fr;
                float v = relu_f(gg[nf] * (acc[mf][nf][j] - m) * rs + bb[nf]);
                hout[(size_t)grow * 256 + col] = v + hres[(size_t)grow * 256 + col];
            }
        }
}

// ---------------- pooling (mean + max per graph) ------------------------------
__global__ void k_pool(const float* __restrict__ h, const int* __restrict__ gstart,
                       const int* __restrict__ gcnt, float* __restrict__ g) {
    int b = blockIdx.x, t = threadIdx.x;
    int st = gstart[b], cnt = gcnt[b];
    float s = 0.f, mx = -3.4e38f;
    for (int i = 0; i < cnt; ++i) {
        float v = h[(size_t)(st + i) * H_DIM + t];
        s += v;
        mx = fmaxf(mx, v);
    }
    float mean = cnt > 0 ? s / (float)cnt : 0.f;
    if (cnt == 0) mx = 0.f;
    g[b * 640 + t] = mean;
    g[b * 640 + 256 + t] = mx;
}

// ---------------- gene projection --------------------------------------------
__global__ void k_gene(const float* __restrict__ gf, const float* __restrict__ Wg1,
                       const float* __restrict__ bg1, const float* __restrict__ lg,
                       const float* __restrict__ lb, const float* __restrict__ Wg2,
                       const float* __restrict__ bg2, float* __restrict__ g) {
    int b = blockIdx.x, t = threadIdx.x;
    __shared__ float xs[GF_DIM];
    __shared__ float sbuf[8];
    __shared__ float s1[H_DIM];
    if (t < GF_DIM) xs[t] = gf[b * GF_DIM + t];
    __syncthreads();
    float acc = bg1[t];
    for (int k = 0; k < GF_DIM; ++k) acc = fmaf(xs[k], Wg1[k * H_DIM + t], acc);
    float mean, rstd;
    ln_stats_256(acc, sbuf, mean, rstd);
    s1[t] = relu_f(lg[t] * (acc - mean) * rstd + lb[t]);
    __syncthreads();
    if (t < 128) {
        float a2 = bg2[t];
        for (int k = 0; k < H_DIM; ++k) a2 = fmaf(s1[k], Wg2[k * 128 + t], a2);
        g[b * 640 + 512 + t] = relu_f(a2);
    }
}

// ---------------- classifier --------------------------------------------------
__global__ void k_cls(const float* __restrict__ g, const float* __restrict__ Wc1,
                      const float* __restrict__ bc1, const float* __restrict__ Wc2,
                      const float* __restrict__ bc2, const float* __restrict__ Wc3,
                      const float* __restrict__ bc3, float* __restrict__ out) {
    int b = blockIdx.x, t = threadIdx.x;
    __shared__ float gg[640];
    __shared__ float s1[256];
    __shared__ float s2[128];
    gg[t] = g[b * 640 + t];
    gg[t + 256] = g[b * 640 + 256 + t];
    if (t < 128) gg[t + 512] = g[b * 640 + 512 + t];
    __syncthreads();
    float a = bc1[t];
    for (int k = 0; k < 640; ++k) a = fmaf(gg[k], Wc1[k * 256 + t], a);
    s1[t] = relu_f(a);
    __syncthreads();
    if (t < 128) {
        float a2 = bc2[t];
        for (int k = 0; k < 256; ++k) a2 = fmaf(s1[k], Wc2[k * 128 + t], a2);
        s2[t] = relu_f(a2);
    }
    __syncthreads();
    if (t < 2) {
        float a3 = bc3[t];
        for (int k = 0; k < 128; ++k) a3 = fmaf(s2[k], Wc3[k * 2 + t], a3);
        out[b * 2 + t] = a3;
    }
}

extern "C" void kernel_launch(void* const* d_in, const int* in_sizes, int n_in,
                              void* d_out, int out_size, void* d_ws, size_t ws_size,
                              hipStream_t stream) {
    const float* x = (const float*)d_in[0];
    const int* ei = (const int*)d_in[1];
    const float* ew = (const float*)d_in[2];
    const int* batch = (const int*)d_in[3];
    const float* gf = (const float*)d_in[4];
    const float* W_in = (const float*)d_in[5];
    const float* b_in = (const float*)d_in[6];
    const float* ln_in_g = (const float*)d_in[7];
    const float* ln_in_b = (const float*)d_in[8];
    const float* eps = (const float*)d_in[9];
    const float* W1 = (const float*)d_in[10];
    const float* b1 = (const float*)d_in[11];
    const float* W2 = (const float*)d_in[12];
    const float* b2 = (const float*)d_in[13];
    const float* ln_g = (const float*)d_in[14];
    const float* ln_b = (const float*)d_in[15];
    const float* Wg1 = (const float*)d_in[16];
    const float* bg1 = (const float*)d_in[17];
    const float* lng_g = (const float*)d_in[18];
    const float* lng_b = (const float*)d_in[19];
    const float* Wg2 = (const float*)d_in[20];
    const float* bg2 = (const float*)d_in[21];
    const float* Wc1 = (const float*)d_in[22];
    const float* bc1 = (const float*)d_in[23];
    const float* Wc2 = (const float*)d_in[24];
    const float* bc2 = (const float*)d_in[25];
    const float* Wc3 = (const float*)d_in[26];
    const float* bc3 = (const float*)d_in[27];
    float* out = (float*)d_out;

    char* ws = (char*)d_ws;
    size_t off = 0;
    auto alloc = [&](size_t bytes) -> char* {
        char* p = ws + off;
        off += (bytes + 255) & ~(size_t)255;
        return p;
    };
    float* H0 = (float*)alloc((size_t)MP * H_DIM * 4);
    float* H1 = (float*)alloc((size_t)MP * H_DIM * 4);
    u16* Ah = (u16*)alloc((size_t)MP * H_DIM * 2);
    u16* Al = (u16*)alloc((size_t)MP * H_DIM * 2);
    u16* C1h = (u16*)alloc((size_t)MP * H2_DIM * 2);
    u16* C1l = (u16*)alloc((size_t)MP * H2_DIM * 2);
    u16* W1Th = (u16*)alloc((size_t)4 * H2_DIM * H_DIM * 2);
    u16* W1Tl = (u16*)alloc((size_t)4 * H2_DIM * H_DIM * 2);
    u16* W2Th = (u16*)alloc((size_t)4 * H_DIM * H2_DIM * 2);
    u16* W2Tl = (u16*)alloc((size_t)4 * H_DIM * H2_DIM * 2);
    int* deg = (int*)alloc(N_NODES * 4);
    int* cursor = (int*)alloc(N_NODES * 4);
    int* gcnt = (int*)alloc(N_B * 4);
    int* row_start = (int*)alloc((N_NODES + 1) * 4);
    int* gstart = (int*)alloc(N_B * 4);
    int* csr_src = (int*)alloc(N_EDGES * 4);
    float* csr_w = (float*)alloc(N_EDGES * 4);
    float* gbuf = (float*)alloc(N_B * 640 * 4);
    (void)ws_size; (void)in_sizes; (void)n_in; (void)out_size;

    // zero deg + cursor + gcnt (contiguous allocations)
    hipMemsetAsync(deg, 0, (size_t)((char*)row_start - (char*)deg), stream);

    // weight transpose + split (tiny)
    k_wprep<<<2048, 256, 0, stream>>>(W1, W1Th, W1Tl, H_DIM, H2_DIM);
    k_wprep<<<2048, 256, 0, stream>>>(W2, W2Th, W2Tl, H2_DIM, H_DIM);

    k_input_proj<<<N_NODES, 256, 0, stream>>>(x, W_in, b_in, ln_in_g, ln_in_b, H0);
    k_hist<<<N_EDGES / 256, 256, 0, stream>>>(ei, deg);
    k_scan<<<1, 1024, 0, stream>>>(deg, row_start);
    k_scatter<<<N_EDGES / 256, 256, 0, stream>>>(ei, ew, row_start, cursor, csr_src, csr_w);
    k_gcount<<<(N_NODES + 255) / 256, 256, 0, stream>>>(batch, gcnt);
    k_gstart<<<1, 128, 0, stream>>>(gcnt, gstart);

    float* hc = H0;
    float* hn = H1;
    for (int l = 0; l < 4; ++l) {
        k_agg<<<N_NODES, 256, 0, stream>>>(hc, row_start, csr_src, csr_w, eps, l, Ah, Al);
        k_mgemm1<<<dim3(MP / 128, 4), 256, 0, stream>>>(
            Ah, Al, W1Th + (size_t)l * H2_DIM * H_DIM, W1Tl + (size_t)l * H2_DIM * H_DIM,
            b1 + (size_t)l * H2_DIM, C1h, C1l);
        k_mgemm2<<<MP / 64, 256, 0, stream>>>(
            C1h, C1l, W2Th + (size_t)l * H_DIM * H2_DIM, W2Tl + (size_t)l * H_DIM * H2_DIM,
            b2 + (size_t)l * H_DIM, ln_g + (size_t)l * H_DIM, ln_b + (size_t)l * H_DIM,
            hc, hn);
        float* tmp = hc; hc = hn; hn = tmp;
    }

    k_pool<<<N_B, 256, 0, stream>>>(hc, gstart, gcnt, gbuf);
    k_gene<<<N_B, 256, 0, stream>>>(gf, Wg1, bg1, lng_g, lng_b, Wg2, bg2, gbuf);
    k_cls<<<N_B, 256, 0, stream>>>(gbuf, Wc1, bc1, Wc2, bc2, Wc3, bc3, out);
}

// Round 4
// 1294.155 us; speedup vs baseline: 1.8224x; 1.2405x over previous
//
#include <hip/hip_runtime.h>
#include <hip/hip_bf16.h>

#define N_NODES 50000
#define MP 50048            // padded row count (multiple of 128)
#define N_EDGES 800000
#define N_B 128
#define H_DIM 256
#define H2_DIM 512
#define FIN_DIM 8
#define GF_DIM 85
#define LN_EPS 1e-5f

typedef unsigned short u16;
typedef unsigned int u32;
typedef __attribute__((ext_vector_type(8))) short bf16x8;
typedef __attribute__((ext_vector_type(4))) float f32x4;

__device__ inline float relu_f(float x) { return x > 0.f ? x : 0.f; }

__device__ inline u16 f2bf(float x) {  // RNE float -> bf16 bits
    u32 u = __float_as_uint(x);
    u32 r = u + 0x7fffu + ((u >> 16) & 1u);
    return (u16)(r >> 16);
}
__device__ inline float bf2f(u16 b) { return __uint_as_float(((u32)b) << 16); }

#define GLOAD16(gp, lp) __builtin_amdgcn_global_load_lds( \
    (const __attribute__((address_space(1))) void*)(gp),  \
    (__attribute__((address_space(3))) void*)(lp), 16, 0, 0)

// LayerNorm stats across a 256-thread block (one value per thread)
__device__ inline void ln_stats_256(float v, float* sbuf, float& mean, float& rstd) {
    float s = v, s2 = v * v;
#pragma unroll
    for (int off = 32; off > 0; off >>= 1) {
        s += __shfl_down(s, off);
        s2 += __shfl_down(s2, off);
    }
    int t = threadIdx.x;
    if ((t & 63) == 0) { sbuf[t >> 6] = s; sbuf[4 + (t >> 6)] = s2; }
    __syncthreads();
    float ts = sbuf[0] + sbuf[1] + sbuf[2] + sbuf[3];
    float ts2 = sbuf[4] + sbuf[5] + sbuf[6] + sbuf[7];
    mean = ts * (1.f / H_DIM);
    float var = ts2 * (1.f / H_DIM) - mean * mean;
    rstd = rsqrtf(var + LN_EPS);
}

// --- input projection: h = relu(LN(x @ W_in + b_in)), split-bf16 out ---------
__global__ void k_input_proj(const float* __restrict__ x, const float* __restrict__ Wi,
                             const float* __restrict__ bi, const float* __restrict__ g,
                             const float* __restrict__ bb,
                             u16* __restrict__ Hh, u16* __restrict__ Hl) {
    int n = blockIdx.x, t = threadIdx.x;
    __shared__ float xs[FIN_DIM];
    __shared__ float sbuf[8];
    if (t < FIN_DIM) xs[t] = x[n * FIN_DIM + t];
    __syncthreads();
    float acc = bi[t];
#pragma unroll
    for (int k = 0; k < FIN_DIM; ++k) acc = fmaf(xs[k], Wi[k * H_DIM + t], acc);
    float mean, rstd;
    ln_stats_256(acc, sbuf, mean, rstd);
    float v = relu_f(g[t] * (acc - mean) * rstd + bb[t]);
    u16 hh = f2bf(v);
    size_t o = (size_t)n * H_DIM + t;
    Hh[o] = hh;
    Hl[o] = f2bf(v - bf2f(hh));
}

// ---------------- CSR build ---------------------------------------------------
__global__ void k_hist(const int* __restrict__ ei, int* __restrict__ deg) {
    int e = blockIdx.x * 256 + threadIdx.x;
    atomicAdd(&deg[ei[N_EDGES + e]], 1);
}

// single block, 1024 threads: sequential-chunk exclusive scan
__global__ void k_scan(const int* __restrict__ deg, int* __restrict__ row_start) {
    __shared__ int s[1024];
    const int t = threadIdx.x;
    const int CH = (N_NODES + 1023) / 1024;  // 49
    int base = t * CH;
    int sum = 0;
    for (int i = 0; i < CH; ++i) {
        int idx = base + i;
        sum += (idx < N_NODES) ? deg[idx] : 0;
    }
    s[t] = sum;
    __syncthreads();
    for (int off = 1; off < 1024; off <<= 1) {
        int xv = (t >= off) ? s[t - off] : 0;
        __syncthreads();
        s[t] += xv;
        __syncthreads();
    }
    int run = s[t] - sum;  // exclusive prefix of this chunk
    for (int i = 0; i < CH; ++i) {
        int idx = base + i;
        if (idx < N_NODES) {
            row_start[idx] = run;
            run += deg[idx];
        }
    }
    if (t == 1023) row_start[N_NODES] = N_EDGES;
}

__global__ void k_scatter(const int* __restrict__ ei, const float* __restrict__ ew,
                          const int* __restrict__ row_start, int* __restrict__ cursor,
                          int* __restrict__ csr_src, float* __restrict__ csr_w) {
    int e = blockIdx.x * 256 + threadIdx.x;
    int d = ei[N_EDGES + e];
    int p = atomicAdd(&cursor[d], 1);
    int i = row_start[d] + p;
    csr_src[i] = ei[e];
    csr_w[i] = ew[e];
}

// batch is sorted: graph b occupies [gstart[b], gstart[b+1])  — binary search
__global__ void k_gbounds(const int* __restrict__ batch, int* __restrict__ gstart,
                          int* __restrict__ gcnt) {
    __shared__ int s[N_B + 1];
    int b = threadIdx.x;  // 0..127
    int lo = 0, hi = N_NODES;
    while (lo < hi) {
        int mid = (lo + hi) >> 1;
        if (batch[mid] < b) lo = mid + 1; else hi = mid;
    }
    s[b] = lo;
    if (b == 0) s[N_B] = N_NODES;
    __syncthreads();
    gstart[b] = s[b];
    gcnt[b] = s[b + 1] - s[b];
}

// ---- GIN aggregation: A = (2+eps)*h + sum_in w*Hh[src], split-bf16 out -------
__global__ void k_agg(const u16* __restrict__ Hh, const u16* __restrict__ Hl,
                      const int* __restrict__ row_start,
                      const int* __restrict__ csr_src, const float* __restrict__ csr_w,
                      const float* __restrict__ eps, int layer,
                      u16* __restrict__ Ah, u16* __restrict__ Al) {
    int n = blockIdx.x, t = threadIdx.x;
    __shared__ int s_src[256];
    __shared__ float s_w[256];
    int start = row_start[n], end = row_start[n + 1];
    float e2 = 2.0f + eps[layer];
    size_t so = (size_t)n * H_DIM + t;
    float hs = bf2f(Hh[so]) + bf2f(Hl[so]);
    float sum = 0.f;
    for (int e0 = start; e0 < end; e0 += 256) {
        int ne = end - e0; if (ne > 256) ne = 256;
        if (t < ne) { s_src[t] = csr_src[e0 + t]; s_w[t] = csr_w[e0 + t]; }
        __syncthreads();
        for (int j = 0; j < ne; ++j)
            sum = fmaf(s_w[j], bf2f(Hh[(size_t)s_src[j] * H_DIM + t]), sum);
        __syncthreads();
    }
    float v = e2 * hs + sum;
    u16 hh = f2bf(v);
    Ah[so] = hh;
    Al[so] = f2bf(v - bf2f(hh));
}

// ------------- weight transpose + split: W[4][R][C] -> T[4][C][R] -------------
__global__ void k_wprep(const float* __restrict__ W, u16* __restrict__ Th,
                        u16* __restrict__ Tl, int R, int C) {
    int idx = blockIdx.x * 256 + threadIdx.x;
    int per = R * C;
    int l = idx / per;
    int rem = idx - l * per;
    int r = rem / C;
    int c = rem - r * C;
    float v = W[idx];
    u16 hh = f2bf(v);
    size_t o = (size_t)l * per + (size_t)c * R + r;
    Th[o] = hh;
    Tl[o] = f2bf(v - bf2f(hh));
}

// ---- MFMA GEMM1: C1 = relu(A[MP,256] @ W1[256,512] + b), split-bf16 io -------
__global__ __launch_bounds__(256, 2) void k_mgemm1(
    const u16* __restrict__ Ah, const u16* __restrict__ Al,
    const u16* __restrict__ Wh, const u16* __restrict__ Wl,
    const float* __restrict__ bias, u16* __restrict__ Ch, u16* __restrict__ Cl) {
    __shared__ __align__(16) u16 sA[2][128 * 32];
    __shared__ __align__(16) u16 sB[2][128 * 32];
    const int t = threadIdx.x;
    const int wv = t >> 6, lane = t & 63;
    const int fr = lane & 15, kg = lane >> 4;
    const int m0 = blockIdx.x * 128, n0 = blockIdx.y * 128;
    const int wm = (wv >> 1) * 64, wn = (wv & 1) * 64;

    f32x4 acc[4][4];
#pragma unroll
    for (int i = 0; i < 4; ++i)
#pragma unroll
        for (int j = 0; j < 4; ++j) acc[i][j] = (f32x4){0.f, 0.f, 0.f, 0.f};

    for (int k0 = 0; k0 < 256; k0 += 32) {
#pragma unroll
        for (int is = 0; is < 2; ++is) {
            int chunk = wv * 128 + is * 64 + lane;
            int r = chunk >> 2, p = chunk & 3;
            size_t ea = (size_t)(m0 + r) * 256 + k0 + p * 8;
            size_t eb = (size_t)(n0 + r) * 256 + k0 + p * 8;
            int lbase = (wv * 128 + is * 64) * 8;
            GLOAD16(Ah + ea, &sA[0][lbase]);
            GLOAD16(Al + ea, &sA[1][lbase]);
            GLOAD16(Wh + eb, &sB[0][lbase]);
            GLOAD16(Wl + eb, &sB[1][lbase]);
        }
        __syncthreads();
        bf16x8 fa[4][2], fb[4][2];
#pragma unroll
        for (int mf = 0; mf < 4; ++mf) {
            int off = (wm + mf * 16 + fr) * 32 + kg * 8;
            fa[mf][0] = *(const bf16x8*)&sA[0][off];
            fa[mf][1] = *(const bf16x8*)&sA[1][off];
        }
#pragma unroll
        for (int nf = 0; nf < 4; ++nf) {
            int off = (wn + nf * 16 + fr) * 32 + kg * 8;
            fb[nf][0] = *(const bf16x8*)&sB[0][off];
            fb[nf][1] = *(const bf16x8*)&sB[1][off];
        }
#pragma unroll
        for (int mf = 0; mf < 4; ++mf)
#pragma unroll
            for (int nf = 0; nf < 4; ++nf) {
                acc[mf][nf] = __builtin_amdgcn_mfma_f32_16x16x32_bf16(fa[mf][0], fb[nf][0], acc[mf][nf], 0, 0, 0);
                acc[mf][nf] = __builtin_amdgcn_mfma_f32_16x16x32_bf16(fa[mf][0], fb[nf][1], acc[mf][nf], 0, 0, 0);
                acc[mf][nf] = __builtin_amdgcn_mfma_f32_16x16x32_bf16(fa[mf][1], fb[nf][0], acc[mf][nf], 0, 0, 0);
            }
        __syncthreads();
    }
#pragma unroll
    for (int nf = 0; nf < 4; ++nf) {
        int col = n0 + wn + nf * 16 + fr;
        float bi = bias[col];
#pragma unroll
        for (int mf = 0; mf < 4; ++mf)
#pragma unroll
            for (int j = 0; j < 4; ++j) {
                int grow = m0 + wm + mf * 16 + kg * 4 + j;
                float v = relu_f(acc[mf][nf][j] + bi);
                u16 hh = f2bf(v);
                u16 ll = f2bf(v - bf2f(hh));
                size_t o = (size_t)grow * 512 + col;
                Ch[o] = hh;
                Cl[o] = ll;
            }
    }
}

// -- MFMA GEMM2 + LN + relu + residual: hout = relu(LN(C1@W2+b2)) + hres -------
__global__ __launch_bounds__(256, 2) void k_mgemm2(
    const u16* __restrict__ Ah, const u16* __restrict__ Al,
    const u16* __restrict__ Wh, const u16* __restrict__ Wl,
    const float* __restrict__ bias, const float* __restrict__ lg,
    const float* __restrict__ lbv,
    const u16* __restrict__ Rh, const u16* __restrict__ Rl,
    u16* __restrict__ Oh, u16* __restrict__ Ol) {
    __shared__ __align__(16) u16 sA[2][64 * 32];
    __shared__ __align__(16) u16 sB[2][256 * 32];
    __shared__ float lnS[64][4], lnS2[64][4];
    __shared__ float lnm[64], lnr[64];
    const int t = threadIdx.x;
    const int wv = t >> 6, lane = t & 63;
    const int fr = lane & 15, kg = lane >> 4;
    const int m0 = blockIdx.x * 64;

    f32x4 acc[4][4];
#pragma unroll
    for (int i = 0; i < 4; ++i)
#pragma unroll
        for (int j = 0; j < 4; ++j) acc[i][j] = (f32x4){0.f, 0.f, 0.f, 0.f};

    for (int k0 = 0; k0 < 512; k0 += 32) {
        {
            int r = t >> 2, p = t & 3;
            size_t ea = (size_t)(m0 + r) * 512 + k0 + p * 8;
            int lbase = (wv * 64) * 8;
            GLOAD16(Ah + ea, &sA[0][lbase]);
            GLOAD16(Al + ea, &sA[1][lbase]);
        }
#pragma unroll
        for (int is = 0; is < 4; ++is) {
            int chunk = is * 256 + t;
            int r = chunk >> 2, p = chunk & 3;
            size_t eb = (size_t)r * 512 + k0 + p * 8;
            int lbase = (is * 256 + wv * 64) * 8;
            GLOAD16(Wh + eb, &sB[0][lbase]);
            GLOAD16(Wl + eb, &sB[1][lbase]);
        }
        __syncthreads();
        bf16x8 fa[4][2], fb[4][2];
#pragma unroll
        for (int mf = 0; mf < 4; ++mf) {
            int off = (mf * 16 + fr) * 32 + kg * 8;
            fa[mf][0] = *(const bf16x8*)&sA[0][off];
            fa[mf][1] = *(const bf16x8*)&sA[1][off];
        }
#pragma unroll
        for (int nf = 0; nf < 4; ++nf) {
            int off = (wv * 64 + nf * 16 + fr) * 32 + kg * 8;
            fb[nf][0] = *(const bf16x8*)&sB[0][off];
            fb[nf][1] = *(const bf16x8*)&sB[1][off];
        }
#pragma unroll
        for (int mf = 0; mf < 4; ++mf)
#pragma unroll
            for (int nf = 0; nf < 4; ++nf) {
                acc[mf][nf] = __builtin_amdgcn_mfma_f32_16x16x32_bf16(fa[mf][0], fb[nf][0], acc[mf][nf], 0, 0, 0);
                acc[mf][nf] = __builtin_amdgcn_mfma_f32_16x16x32_bf16(fa[mf][0], fb[nf][1], acc[mf][nf], 0, 0, 0);
                acc[mf][nf] = __builtin_amdgcn_mfma_f32_16x16x32_bf16(fa[mf][1], fb[nf][0], acc[mf][nf], 0, 0, 0);
            }
        __syncthreads();
    }
    float bcol[4];
#pragma unroll
    for (int nf = 0; nf < 4; ++nf) bcol[nf] = bias[wv * 64 + nf * 16 + fr];
#pragma unroll
    for (int mf = 0; mf < 4; ++mf)
#pragma unroll
        for (int nf = 0; nf < 4; ++nf)
#pragma unroll
            for (int j = 0; j < 4; ++j) acc[mf][nf][j] += bcol[nf];
#pragma unroll
    for (int mf = 0; mf < 4; ++mf)
#pragma unroll
        for (int j = 0; j < 4; ++j) {
            float s = acc[mf][0][j] + acc[mf][1][j] + acc[mf][2][j] + acc[mf][3][j];
            float s2 = acc[mf][0][j] * acc[mf][0][j] + acc[mf][1][j] * acc[mf][1][j] +
                       acc[mf][2][j] * acc[mf][2][j] + acc[mf][3][j] * acc[mf][3][j];
#pragma unroll
            for (int off = 1; off < 16; off <<= 1) {
                s += __shfl_xor(s, off);
                s2 += __shfl_xor(s2, off);
            }
            if (fr == 0) {
                int row = mf * 16 + kg * 4 + j;
                lnS[row][wv] = s;
                lnS2[row][wv] = s2;
            }
        }
    __syncthreads();
    if (t < 64) {
        float s = lnS[t][0] + lnS[t][1] + lnS[t][2] + lnS[t][3];
        float s2 = lnS2[t][0] + lnS2[t][1] + lnS2[t][2] + lnS2[t][3];
        float m = s * (1.f / 256.f);
        float var = s2 * (1.f / 256.f) - m * m;
        lnm[t] = m;
        lnr[t] = rsqrtf(var + LN_EPS);
    }
    __syncthreads();
    float gg[4], bb[4];
#pragma unroll
    for (int nf = 0; nf < 4; ++nf) {
        int col = wv * 64 + nf * 16 + fr;
        gg[nf] = lg[col];
        bb[nf] = lbv[col];
    }
#pragma unroll
    for (int mf = 0; mf < 4; ++mf)
#pragma unroll
        for (int j = 0; j < 4; ++j) {
            int row = mf * 16 + kg * 4 + j;
            int grow = m0 + row;
            float m = lnm[row], rs = lnr[row];
#pragma unroll
            for (int nf = 0; nf < 4; ++nf) {
                int col = wv * 64 + nf * 16 + fr;
                size_t o = (size_t)grow * 256 + col;
                float res = bf2f(Rh[o]) + bf2f(Rl[o]);
                float v = relu_f(gg[nf] * (acc[mf][nf][j] - m) * rs + bb[nf]) + res;
                u16 hh = f2bf(v);
                Oh[o] = hh;
                Ol[o] = f2bf(v - bf2f(hh));
            }
        }
}

// -------- pooling (mean + max per graph), 4 col-chunks x 4-way rows -----------
__global__ void k_pool(const u16* __restrict__ Hh, const u16* __restrict__ Hl,
                       const int* __restrict__ gstart,
                       const int* __restrict__ gcnt, float* __restrict__ g) {
    int b = blockIdx.x;
    int col = blockIdx.y * 64 + (threadIdx.x & 63);
    int r = threadIdx.x >> 6;
    int st = gstart[b], cnt = gcnt[b];
    float s = 0.f, mx = -3.4e38f;
    for (int i = r; i < cnt; i += 4) {
        size_t o = (size_t)(st + i) * H_DIM + col;
        float v = bf2f(Hh[o]) + bf2f(Hl[o]);
        s += v;
        mx = fmaxf(mx, v);
    }
    __shared__ float ss[256], sm[256];
    ss[threadIdx.x] = s;
    sm[threadIdx.x] = mx;
    __syncthreads();
    if (r == 0) {
#pragma unroll
        for (int k = 1; k < 4; ++k) {
            s += ss[threadIdx.x + 64 * k];
            mx = fmaxf(mx, sm[threadIdx.x + 64 * k]);
        }
        float mean = cnt > 0 ? s / (float)cnt : 0.f;
        if (cnt == 0) mx = 0.f;
        g[b * 640 + col] = mean;
        g[b * 640 + 256 + col] = mx;
    }
}

// ---------------- gene projection --------------------------------------------
__global__ void k_gene(const float* __restrict__ gf, const float* __restrict__ Wg1,
                       const float* __restrict__ bg1, const float* __restrict__ lg,
                       const float* __restrict__ lb, const float* __restrict__ Wg2,
                       const float* __restrict__ bg2, float* __restrict__ g) {
    int b = blockIdx.x, t = threadIdx.x;
    __shared__ float xs[GF_DIM];
    __shared__ float sbuf[8];
    __shared__ float s1[H_DIM];
    if (t < GF_DIM) xs[t] = gf[b * GF_DIM + t];
    __syncthreads();
    float acc = bg1[t];
    for (int k = 0; k < GF_DIM; ++k) acc = fmaf(xs[k], Wg1[k * H_DIM + t], acc);
    float mean, rstd;
    ln_stats_256(acc, sbuf, mean, rstd);
    s1[t] = relu_f(lg[t] * (acc - mean) * rstd + lb[t]);
    __syncthreads();
    if (t < 128) {
        float a2 = bg2[t];
        for (int k = 0; k < H_DIM; ++k) a2 = fmaf(s1[k], Wg2[k * 128 + t], a2);
        g[b * 640 + 512 + t] = relu_f(a2);
    }
}

// ---------------- classifier --------------------------------------------------
__global__ void k_cls(const float* __restrict__ g, const float* __restrict__ Wc1,
                      const float* __restrict__ bc1, const float* __restrict__ Wc2,
                      const float* __restrict__ bc2, const float* __restrict__ Wc3,
                      const float* __restrict__ bc3, float* __restrict__ out) {
    int b = blockIdx.x, t = threadIdx.x;
    __shared__ float gg[640];
    __shared__ float s1[256];
    __shared__ float s2[128];
    gg[t] = g[b * 640 + t];
    gg[t + 256] = g[b * 640 + 256 + t];
    if (t < 128) gg[t + 512] = g[b * 640 + 512 + t];
    __syncthreads();
    float a = bc1[t];
    for (int k = 0; k < 640; ++k) a = fmaf(gg[k], Wc1[k * 256 + t], a);
    s1[t] = relu_f(a);
    __syncthreads();
    if (t < 128) {
        float a2 = bc2[t];
        for (int k = 0; k < 256; ++k) a2 = fmaf(s1[k], Wc2[k * 128 + t], a2);
        s2[t] = relu_f(a2);
    }
    __syncthreads();
    if (t < 2) {
        float a3 = bc3[t];
        for (int k = 0; k < 128; ++k) a3 = fmaf(s2[k], Wc3[k * 2 + t], a3);
        out[b * 2 + t] = a3;
    }
}

extern "C" void kernel_launch(void* const* d_in, const int* in_sizes, int n_in,
                              void* d_out, int out_size, void* d_ws, size_t ws_size,
                              hipStream_t stream) {
    const float* x = (const float*)d_in[0];
    const int* ei = (const int*)d_in[1];
    const float* ew = (const float*)d_in[2];
    const int* batch = (const int*)d_in[3];
    const float* gf = (const float*)d_in[4];
    const float* W_in = (const float*)d_in[5];
    const float* b_in = (const float*)d_in[6];
    const float* ln_in_g = (const float*)d_in[7];
    const float* ln_in_b = (const float*)d_in[8];
    const float* eps = (const float*)d_in[9];
    const float* W1 = (const float*)d_in[10];
    const float* b1 = (const float*)d_in[11];
    const float* W2 = (const float*)d_in[12];
    const float* b2 = (const float*)d_in[13];
    const float* ln_g = (const float*)d_in[14];
    const float* ln_b = (const float*)d_in[15];
    const float* Wg1 = (const float*)d_in[16];
    const float* bg1 = (const float*)d_in[17];
    const float* lng_g = (const float*)d_in[18];
    const float* lng_b = (const float*)d_in[19];
    const float* Wg2 = (const float*)d_in[20];
    const float* bg2 = (const float*)d_in[21];
    const float* Wc1 = (const float*)d_in[22];
    const float* bc1 = (const float*)d_in[23];
    const float* Wc2 = (const float*)d_in[24];
    const float* bc2 = (const float*)d_in[25];
    const float* Wc3 = (const float*)d_in[26];
    const float* bc3 = (const float*)d_in[27];
    float* out = (float*)d_out;

    char* ws = (char*)d_ws;
    size_t off = 0;
    auto alloc = [&](size_t bytes) -> char* {
        char* p = ws + off;
        off += (bytes + 255) & ~(size_t)255;
        return p;
    };
    u16* Hh0 = (u16*)alloc((size_t)MP * H_DIM * 2);
    u16* Hl0 = (u16*)alloc((size_t)MP * H_DIM * 2);
    u16* Hh1 = (u16*)alloc((size_t)MP * H_DIM * 2);
    u16* Hl1 = (u16*)alloc((size_t)MP * H_DIM * 2);
    u16* Ah = (u16*)alloc((size_t)MP * H_DIM * 2);
    u16* Al = (u16*)alloc((size_t)MP * H_DIM * 2);
    u16* C1h = (u16*)alloc((size_t)MP * H2_DIM * 2);
    u16* C1l = (u16*)alloc((size_t)MP * H2_DIM * 2);
    u16* W1Th = (u16*)alloc((size_t)4 * H2_DIM * H_DIM * 2);
    u16* W1Tl = (u16*)alloc((size_t)4 * H2_DIM * H_DIM * 2);
    u16* W2Th = (u16*)alloc((size_t)4 * H_DIM * H2_DIM * 2);
    u16* W2Tl = (u16*)alloc((size_t)4 * H_DIM * H2_DIM * 2);
    int* deg = (int*)alloc(N_NODES * 4);
    int* cursor = (int*)alloc(N_NODES * 4);
    int* row_start = (int*)alloc((N_NODES + 1) * 4);
    int* gcnt = (int*)alloc(N_B * 4);
    int* gstart = (int*)alloc(N_B * 4);
    int* csr_src = (int*)alloc(N_EDGES * 4);
    float* csr_w = (float*)alloc(N_EDGES * 4);
    float* gbuf = (float*)alloc(N_B * 640 * 4);
    (void)ws_size; (void)in_sizes; (void)n_in; (void)out_size;

    // zero deg + cursor — span computed from pointers so padding is covered
    hipMemsetAsync(deg, 0, (size_t)((char*)row_start - (char*)deg), stream);

    // weight transpose + split (tiny)
    k_wprep<<<2048, 256, 0, stream>>>(W1, W1Th, W1Tl, H_DIM, H2_DIM);
    k_wprep<<<2048, 256, 0, stream>>>(W2, W2Th, W2Tl, H2_DIM, H_DIM);

    k_input_proj<<<N_NODES, 256, 0, stream>>>(x, W_in, b_in, ln_in_g, ln_in_b, Hh0, Hl0);
    k_hist<<<N_EDGES / 256, 256, 0, stream>>>(ei, deg);
    k_scan<<<1, 1024, 0, stream>>>(deg, row_start);
    k_scatter<<<N_EDGES / 256, 256, 0, stream>>>(ei, ew, row_start, cursor, csr_src, csr_w);
    k_gbounds<<<1, N_B, 0, stream>>>(batch, gstart, gcnt);

    u16* hch = Hh0; u16* hcl = Hl0;
    u16* hnh = Hh1; u16* hnl = Hl1;
    for (int l = 0; l < 4; ++l) {
        k_agg<<<N_NODES, 256, 0, stream>>>(hch, hcl, row_start, csr_src, csr_w, eps, l, Ah, Al);
        k_mgemm1<<<dim3(MP / 128, 4), 256, 0, stream>>>(
            Ah, Al, W1Th + (size_t)l * H2_DIM * H_DIM, W1Tl + (size_t)l * H2_DIM * H_DIM,
            b1 + (size_t)l * H2_DIM, C1h, C1l);
        k_mgemm2<<<MP / 64, 256, 0, stream>>>(
            C1h, C1l, W2Th + (size_t)l * H_DIM * H2_DIM, W2Tl + (size_t)l * H_DIM * H2_DIM,
            b2 + (size_t)l * H_DIM, ln_g + (size_t)l * H_DIM, ln_b + (size_t)l * H_DIM,
            hch, hcl, hnh, hnl);
        u16* th = hch; hch = hnh; hnh = th;
        u16* tl = hcl; hcl = hnl; hnl = tl;
    }

    k_pool<<<dim3(N_B, 4), 256, 0, stream>>>(hch, hcl, gstart, gcnt, gbuf);
    k_gene<<<N_B, 256, 0, stream>>>(gf, Wg1, bg1, lng_g, lng_b, Wg2, bg2, gbuf);
    k_cls<<<N_B, 256, 0, stream>>>(gbuf, Wc1, bc1, Wc2, bc2, Wc3, bc3, out);
}

// Round 5
// 1084.624 us; speedup vs baseline: 2.1744x; 1.1932x over previous
//
#include <hip/hip_runtime.h>
#include <hip/hip_bf16.h>

#define N_NODES 50000
#define MP 50048            // padded row count (multiple of 128)
#define N_EDGES 800000
#define N_B 128
#define H_DIM 256
#define H2_DIM 512
#define FIN_DIM 8
#define GF_DIM 85
#define LN_EPS 1e-5f
#define SCAN_NBLK 196       // ceil(50000/256)

typedef unsigned short u16;
typedef unsigned int u32;
typedef _Float16 f16;
typedef __attribute__((ext_vector_type(8))) _Float16 f16x8;
typedef __attribute__((ext_vector_type(4))) float f32x4;

__device__ inline float relu_f(float x) { return x > 0.f ? x : 0.f; }

__device__ inline float h2f(u16 b) { f16 h; __builtin_memcpy(&h, &b, 2); return (float)h; }
__device__ inline u16 f2h(float x) { f16 h = (f16)x; u16 b; __builtin_memcpy(&b, &h, 2); return b; }

#define GLOAD16(gp, lp) __builtin_amdgcn_global_load_lds( \
    (const __attribute__((address_space(1))) void*)(gp),  \
    (__attribute__((address_space(3))) void*)(lp), 16, 0, 0)

// LayerNorm stats across a 256-thread block (one value per thread)
__device__ inline void ln_stats_256(float v, float* sbuf, float& mean, float& rstd) {
    float s = v, s2 = v * v;
#pragma unroll
    for (int off = 32; off > 0; off >>= 1) {
        s += __shfl_down(s, off);
        s2 += __shfl_down(s2, off);
    }
    int t = threadIdx.x;
    if ((t & 63) == 0) { sbuf[t >> 6] = s; sbuf[4 + (t >> 6)] = s2; }
    __syncthreads();
    float ts = sbuf[0] + sbuf[1] + sbuf[2] + sbuf[3];
    float ts2 = sbuf[4] + sbuf[5] + sbuf[6] + sbuf[7];
    mean = ts * (1.f / H_DIM);
    float var = ts2 * (1.f / H_DIM) - mean * mean;
    rstd = rsqrtf(var + LN_EPS);
}

// --- input projection: h = relu(LN(x @ W_in + b_in)), split-fp16 out ---------
__global__ void k_input_proj(const float* __restrict__ x, const float* __restrict__ Wi,
                             const float* __restrict__ bi, const float* __restrict__ g,
                             const float* __restrict__ bb,
                             u16* __restrict__ Hh, u16* __restrict__ Hl) {
    int n = blockIdx.x, t = threadIdx.x;
    __shared__ float xs[FIN_DIM];
    __shared__ float sbuf[8];
    if (t < FIN_DIM) xs[t] = x[n * FIN_DIM + t];
    __syncthreads();
    float acc = bi[t];
#pragma unroll
    for (int k = 0; k < FIN_DIM; ++k) acc = fmaf(xs[k], Wi[k * H_DIM + t], acc);
    float mean, rstd;
    ln_stats_256(acc, sbuf, mean, rstd);
    float v = relu_f(g[t] * (acc - mean) * rstd + bb[t]);
    u16 hh = f2h(v);
    size_t o = (size_t)n * H_DIM + t;
    Hh[o] = hh;
    Hl[o] = f2h(v - h2f(hh));
}

// ---------------- CSR build ---------------------------------------------------
__global__ void k_hist(const int* __restrict__ ei, int* __restrict__ deg) {
    int e = blockIdx.x * 256 + threadIdx.x;
    atomicAdd(&deg[ei[N_EDGES + e]], 1);
}

// 3-stage parallel exclusive scan of deg -> row_start
__global__ void k_scan1(const int* __restrict__ deg, int* __restrict__ row_start,
                        int* __restrict__ bsum) {
    __shared__ int s[256];
    int t = threadIdx.x, i = blockIdx.x * 256 + t;
    int v = (i < N_NODES) ? deg[i] : 0;
    s[t] = v;
    __syncthreads();
    for (int off = 1; off < 256; off <<= 1) {
        int x = (t >= off) ? s[t - off] : 0;
        __syncthreads();
        s[t] += x;
        __syncthreads();
    }
    if (i < N_NODES) row_start[i] = s[t] - v;  // exclusive within block
    if (t == 255) bsum[blockIdx.x] = s[255];
}

__global__ void k_scan2(int* __restrict__ bsum) {
    __shared__ int s[256];
    int t = threadIdx.x;
    int v = (t < SCAN_NBLK) ? bsum[t] : 0;
    s[t] = v;
    __syncthreads();
    for (int off = 1; off < 256; off <<= 1) {
        int x = (t >= off) ? s[t - off] : 0;
        __syncthreads();
        s[t] += x;
        __syncthreads();
    }
    if (t < SCAN_NBLK) bsum[t] = s[t] - v;  // exclusive block offsets
}

__global__ void k_scan3(int* __restrict__ row_start, const int* __restrict__ bsum) {
    int t = threadIdx.x, i = blockIdx.x * 256 + t;
    if (i < N_NODES) row_start[i] += bsum[blockIdx.x];
    if (i == 0) row_start[N_NODES] = N_EDGES;
}

__global__ void k_scatter(const int* __restrict__ ei, const float* __restrict__ ew,
                          const int* __restrict__ row_start, int* __restrict__ cursor,
                          int* __restrict__ csr_src, float* __restrict__ csr_w) {
    int e = blockIdx.x * 256 + threadIdx.x;
    int d = ei[N_EDGES + e];
    int p = atomicAdd(&cursor[d], 1);
    int i = row_start[d] + p;
    csr_src[i] = ei[e];
    csr_w[i] = ew[e];
}

// batch is sorted: graph b occupies [gstart[b], gstart[b+1])  — binary search
__global__ void k_gbounds(const int* __restrict__ batch, int* __restrict__ gstart,
                          int* __restrict__ gcnt) {
    __shared__ int s[N_B + 1];
    int b = threadIdx.x;  // 0..127
    int lo = 0, hi = N_NODES;
    while (lo < hi) {
        int mid = (lo + hi) >> 1;
        if (batch[mid] < b) lo = mid + 1; else hi = mid;
    }
    s[b] = lo;
    if (b == 0) s[N_B] = N_NODES;
    __syncthreads();
    gstart[b] = s[b];
    gcnt[b] = s[b + 1] - s[b];
}

// ---- GIN aggregation: A = (2+eps)*h + sum_in w*Hh[src], split-fp16 out -------
// wave-per-edge: each wave loads a full 512B row (8 B/lane), 4-wave LDS combine
__global__ void k_agg(const u16* __restrict__ Hh, const u16* __restrict__ Hl,
                      const int* __restrict__ row_start,
                      const int* __restrict__ csr_src, const float* __restrict__ csr_w,
                      const float* __restrict__ eps, int layer,
                      u16* __restrict__ Ah, u16* __restrict__ Al) {
    const int n = blockIdx.x, t = threadIdx.x, wv = t >> 6, lane = t & 63;
    __shared__ int s_src[256];
    __shared__ float s_w[256];
    __shared__ float part[4][256];
    int start = row_start[n], end = row_start[n + 1];
    float a0 = 0.f, a1 = 0.f, a2 = 0.f, a3 = 0.f;
    for (int e0 = start; e0 < end; e0 += 256) {
        int ne = end - e0; if (ne > 256) ne = 256;
        if (t < ne) { s_src[t] = csr_src[e0 + t]; s_w[t] = csr_w[e0 + t]; }
        __syncthreads();
        for (int j = wv; j < ne; j += 4) {
            int src = s_src[j];
            float w = s_w[j];
            ushort4 v = *reinterpret_cast<const ushort4*>(&Hh[(size_t)src * H_DIM + lane * 4]);
            a0 = fmaf(w, h2f(v.x), a0);
            a1 = fmaf(w, h2f(v.y), a1);
            a2 = fmaf(w, h2f(v.z), a2);
            a3 = fmaf(w, h2f(v.w), a3);
        }
        __syncthreads();
    }
    *reinterpret_cast<float4*>(&part[wv][lane * 4]) = (float4){a0, a1, a2, a3};
    __syncthreads();
    float sum = part[0][t] + part[1][t] + part[2][t] + part[3][t];
    size_t so = (size_t)n * H_DIM + t;
    float e2 = 2.0f + eps[layer];
    float hs = h2f(Hh[so]) + h2f(Hl[so]);
    float v = e2 * hs + sum;
    u16 hh = f2h(v);
    Ah[so] = hh;
    Al[so] = f2h(v - h2f(hh));
}

// ---- weight transpose -> fp16: T[l][c][r] = f16(W[l][r][c]), coalesced -------
__global__ void k_wprep(const float* __restrict__ W, u16* __restrict__ T, int R, int C) {
    __shared__ float tile[64][65];
    int c0 = blockIdx.x * 64, r0 = blockIdx.y * 64;
    const float* Wl = W + (size_t)blockIdx.z * R * C;
    u16* Tl_ = T + (size_t)blockIdx.z * R * C;
    int t = threadIdx.x;
    int col = t & 63, qr = t >> 6;
#pragma unroll
    for (int i = 0; i < 16; ++i) {
        int row = i * 4 + qr;
        tile[row][col] = Wl[(size_t)(r0 + row) * C + c0 + col];
    }
    __syncthreads();
#pragma unroll
    for (int i = 0; i < 16; ++i) {
        int crow = i * 4 + qr;  // transposed row = original col
        Tl_[(size_t)(c0 + crow) * R + r0 + col] = f2h(tile[col][crow]);
    }
}

// ---- MFMA GEMM1: C1 = relu(A[MP,256] @ W1[256,512] + b), split-fp16 io -------
// A split (Ah,Al) [MP][256]; W1T fp16 [512][256]; out C1 split [MP][512]
__global__ __launch_bounds__(256, 2) void k_mgemm1(
    const u16* __restrict__ Ah, const u16* __restrict__ Al,
    const u16* __restrict__ Wt,
    const float* __restrict__ bias, u16* __restrict__ Ch, u16* __restrict__ Cl) {
    __shared__ __align__(16) u16 sA[2][128 * 32];
    __shared__ __align__(16) u16 sB[128 * 32];
    const int t = threadIdx.x;
    const int wv = t >> 6, lane = t & 63;
    const int fr = lane & 15, kg = lane >> 4;
    const int m0 = blockIdx.x * 128, n0 = blockIdx.y * 128;
    const int wm = (wv >> 1) * 64, wn = (wv & 1) * 64;

    f32x4 acc[4][4];
#pragma unroll
    for (int i = 0; i < 4; ++i)
#pragma unroll
        for (int j = 0; j < 4; ++j) acc[i][j] = (f32x4){0.f, 0.f, 0.f, 0.f};

    for (int k0 = 0; k0 < 256; k0 += 32) {
#pragma unroll
        for (int is = 0; is < 2; ++is) {
            int chunk = wv * 128 + is * 64 + lane;
            int r = chunk >> 2, p = chunk & 3;
            size_t ea = (size_t)(m0 + r) * 256 + k0 + p * 8;
            size_t eb = (size_t)(n0 + r) * 256 + k0 + p * 8;
            int lbase = (wv * 128 + is * 64) * 8;
            GLOAD16(Ah + ea, &sA[0][lbase]);
            GLOAD16(Al + ea, &sA[1][lbase]);
            GLOAD16(Wt + eb, &sB[lbase]);
        }
        __syncthreads();
        f16x8 fa[4][2], fb[4];
#pragma unroll
        for (int mf = 0; mf < 4; ++mf) {
            int off = (wm + mf * 16 + fr) * 32 + kg * 8;
            fa[mf][0] = *(const f16x8*)&sA[0][off];
            fa[mf][1] = *(const f16x8*)&sA[1][off];
        }
#pragma unroll
        for (int nf = 0; nf < 4; ++nf) {
            int off = (wn + nf * 16 + fr) * 32 + kg * 8;
            fb[nf] = *(const f16x8*)&sB[off];
        }
#pragma unroll
        for (int mf = 0; mf < 4; ++mf)
#pragma unroll
            for (int nf = 0; nf < 4; ++nf) {
                acc[mf][nf] = __builtin_amdgcn_mfma_f32_16x16x32_f16(fa[mf][0], fb[nf], acc[mf][nf], 0, 0, 0);
                acc[mf][nf] = __builtin_amdgcn_mfma_f32_16x16x32_f16(fa[mf][1], fb[nf], acc[mf][nf], 0, 0, 0);
            }
        __syncthreads();
    }
#pragma unroll
    for (int nf = 0; nf < 4; ++nf) {
        int col = n0 + wn + nf * 16 + fr;
        float bi = bias[col];
#pragma unroll
        for (int mf = 0; mf < 4; ++mf)
#pragma unroll
            for (int j = 0; j < 4; ++j) {
                int grow = m0 + wm + mf * 16 + kg * 4 + j;
                float v = relu_f(acc[mf][nf][j] + bi);
                u16 hh = f2h(v);
                u16 ll = f2h(v - h2f(hh));
                size_t o = (size_t)grow * 512 + col;
                Ch[o] = hh;
                Cl[o] = ll;
            }
    }
}

// -- MFMA GEMM2 + LN + relu + residual: hout = relu(LN(C1@W2+b2)) + hres -------
__global__ __launch_bounds__(256, 2) void k_mgemm2(
    const u16* __restrict__ Ah, const u16* __restrict__ Al,
    const u16* __restrict__ Wt,
    const float* __restrict__ bias, const float* __restrict__ lg,
    const float* __restrict__ lbv,
    const u16* __restrict__ Rh, const u16* __restrict__ Rl,
    u16* __restrict__ Oh, u16* __restrict__ Ol) {
    __shared__ __align__(16) u16 sA[2][64 * 32];
    __shared__ __align__(16) u16 sB[256 * 32];
    __shared__ float lnS[64][4], lnS2[64][4];
    __shared__ float lnm[64], lnr[64];
    const int t = threadIdx.x;
    const int wv = t >> 6, lane = t & 63;
    const int fr = lane & 15, kg = lane >> 4;
    const int m0 = blockIdx.x * 64;

    f32x4 acc[4][4];
#pragma unroll
    for (int i = 0; i < 4; ++i)
#pragma unroll
        for (int j = 0; j < 4; ++j) acc[i][j] = (f32x4){0.f, 0.f, 0.f, 0.f};

    for (int k0 = 0; k0 < 512; k0 += 32) {
        {
            int r = t >> 2, p = t & 3;
            size_t ea = (size_t)(m0 + r) * 512 + k0 + p * 8;
            int lbase = (wv * 64) * 8;
            GLOAD16(Ah + ea, &sA[0][lbase]);
            GLOAD16(Al + ea, &sA[1][lbase]);
        }
#pragma unroll
        for (int is = 0; is < 4; ++is) {
            int chunk = is * 256 + t;
            int r = chunk >> 2, p = chunk & 3;
            size_t eb = (size_t)r * 512 + k0 + p * 8;
            int lbase = (is * 256 + wv * 64) * 8;
            GLOAD16(Wt + eb, &sB[lbase]);
        }
        __syncthreads();
        f16x8 fa[4][2], fb[4];
#pragma unroll
        for (int mf = 0; mf < 4; ++mf) {
            int off = (mf * 16 + fr) * 32 + kg * 8;
            fa[mf][0] = *(const f16x8*)&sA[0][off];
            fa[mf][1] = *(const f16x8*)&sA[1][off];
        }
#pragma unroll
        for (int nf = 0; nf < 4; ++nf) {
            int off = (wv * 64 + nf * 16 + fr) * 32 + kg * 8;
            fb[nf] = *(const f16x8*)&sB[off];
        }
#pragma unroll
        for (int mf = 0; mf < 4; ++mf)
#pragma unroll
            for (int nf = 0; nf < 4; ++nf) {
                acc[mf][nf] = __builtin_amdgcn_mfma_f32_16x16x32_f16(fa[mf][0], fb[nf], acc[mf][nf], 0, 0, 0);
                acc[mf][nf] = __builtin_amdgcn_mfma_f32_16x16x32_f16(fa[mf][1], fb[nf], acc[mf][nf], 0, 0, 0);
            }
        __syncthreads();
    }
    float bcol[4];
#pragma unroll
    for (int nf = 0; nf < 4; ++nf) bcol[nf] = bias[wv * 64 + nf * 16 + fr];
#pragma unroll
    for (int mf = 0; mf < 4; ++mf)
#pragma unroll
        for (int nf = 0; nf < 4; ++nf)
#pragma unroll
            for (int j = 0; j < 4; ++j) acc[mf][nf][j] += bcol[nf];
#pragma unroll
    for (int mf = 0; mf < 4; ++mf)
#pragma unroll
        for (int j = 0; j < 4; ++j) {
            float s = acc[mf][0][j] + acc[mf][1][j] + acc[mf][2][j] + acc[mf][3][j];
            float s2 = acc[mf][0][j] * acc[mf][0][j] + acc[mf][1][j] * acc[mf][1][j] +
                       acc[mf][2][j] * acc[mf][2][j] + acc[mf][3][j] * acc[mf][3][j];
#pragma unroll
            for (int off = 1; off < 16; off <<= 1) {
                s += __shfl_xor(s, off);
                s2 += __shfl_xor(s2, off);
            }
            if (fr == 0) {
                int row = mf * 16 + kg * 4 + j;
                lnS[row][wv] = s;
                lnS2[row][wv] = s2;
            }
        }
    __syncthreads();
    if (t < 64) {
        float s = lnS[t][0] + lnS[t][1] + lnS[t][2] + lnS[t][3];
        float s2 = lnS2[t][0] + lnS2[t][1] + lnS2[t][2] + lnS2[t][3];
        float m = s * (1.f / 256.f);
        float var = s2 * (1.f / 256.f) - m * m;
        lnm[t] = m;
        lnr[t] = rsqrtf(var + LN_EPS);
    }
    __syncthreads();
    float gg[4], bb[4];
#pragma unroll
    for (int nf = 0; nf < 4; ++nf) {
        int col = wv * 64 + nf * 16 + fr;
        gg[nf] = lg[col];
        bb[nf] = lbv[col];
    }
#pragma unroll
    for (int mf = 0; mf < 4; ++mf)
#pragma unroll
        for (int j = 0; j < 4; ++j) {
            int row = mf * 16 + kg * 4 + j;
            int grow = m0 + row;
            float m = lnm[row], rs = lnr[row];
#pragma unroll
            for (int nf = 0; nf < 4; ++nf) {
                int col = wv * 64 + nf * 16 + fr;
                size_t o = (size_t)grow * 256 + col;
                float res = h2f(Rh[o]) + h2f(Rl[o]);
                float v = relu_f(gg[nf] * (acc[mf][nf][j] - m) * rs + bb[nf]) + res;
                u16 hh = f2h(v);
                Oh[o] = hh;
                Ol[o] = f2h(v - h2f(hh));
            }
        }
}

// -------- pooling (mean + max per graph), 4 col-chunks x 4-way rows -----------
__global__ void k_pool(const u16* __restrict__ Hh, const u16* __restrict__ Hl,
                       const int* __restrict__ gstart,
                       const int* __restrict__ gcnt, float* __restrict__ g) {
    int b = blockIdx.x;
    int col = blockIdx.y * 64 + (threadIdx.x & 63);
    int r = threadIdx.x >> 6;
    int st = gstart[b], cnt = gcnt[b];
    float s = 0.f, mx = -3.4e38f;
    for (int i = r; i < cnt; i += 4) {
        size_t o = (size_t)(st + i) * H_DIM + col;
        float v = h2f(Hh[o]) + h2f(Hl[o]);
        s += v;
        mx = fmaxf(mx, v);
    }
    __shared__ float ss[256], sm[256];
    ss[threadIdx.x] = s;
    sm[threadIdx.x] = mx;
    __syncthreads();
    if (r == 0) {
#pragma unroll
        for (int k = 1; k < 4; ++k) {
            s += ss[threadIdx.x + 64 * k];
            mx = fmaxf(mx, sm[threadIdx.x + 64 * k]);
        }
        float mean = cnt > 0 ? s / (float)cnt : 0.f;
        if (cnt == 0) mx = 0.f;
        g[b * 640 + col] = mean;
        g[b * 640 + 256 + col] = mx;
    }
}

// ---------------- gene projection --------------------------------------------
__global__ void k_gene(const float* __restrict__ gf, const float* __restrict__ Wg1,
                       const float* __restrict__ bg1, const float* __restrict__ lg,
                       const float* __restrict__ lb, const float* __restrict__ Wg2,
                       const float* __restrict__ bg2, float* __restrict__ g) {
    int b = blockIdx.x, t = threadIdx.x;
    __shared__ float xs[GF_DIM];
    __shared__ float sbuf[8];
    __shared__ float s1[H_DIM];
    if (t < GF_DIM) xs[t] = gf[b * GF_DIM + t];
    __syncthreads();
    float acc = bg1[t];
    for (int k = 0; k < GF_DIM; ++k) acc = fmaf(xs[k], Wg1[k * H_DIM + t], acc);
    float mean, rstd;
    ln_stats_256(acc, sbuf, mean, rstd);
    s1[t] = relu_f(lg[t] * (acc - mean) * rstd + lb[t]);
    __syncthreads();
    if (t < 128) {
        float a2 = bg2[t];
        for (int k = 0; k < H_DIM; ++k) a2 = fmaf(s1[k], Wg2[k * 128 + t], a2);
        g[b * 640 + 512 + t] = relu_f(a2);
    }
}

// ---------------- classifier --------------------------------------------------
__global__ void k_cls(const float* __restrict__ g, const float* __restrict__ Wc1,
                      const float* __restrict__ bc1, const float* __restrict__ Wc2,
                      const float* __restrict__ bc2, const float* __restrict__ Wc3,
                      const float* __restrict__ bc3, float* __restrict__ out) {
    int b = blockIdx.x, t = threadIdx.x;
    __shared__ float gg[640];
    __shared__ float s1[256];
    __shared__ float s2[128];
    gg[t] = g[b * 640 + t];
    gg[t + 256] = g[b * 640 + 256 + t];
    if (t < 128) gg[t + 512] = g[b * 640 + 512 + t];
    __syncthreads();
    float a = bc1[t];
    for (int k = 0; k < 640; ++k) a = fmaf(gg[k], Wc1[k * 256 + t], a);
    s1[t] = relu_f(a);
    __syncthreads();
    if (t < 128) {
        float a2 = bc2[t];
        for (int k = 0; k < 256; ++k) a2 = fmaf(s1[k], Wc2[k * 128 + t], a2);
        s2[t] = relu_f(a2);
    }
    __syncthreads();
    if (t < 2) {
        float a3 = bc3[t];
        for (int k = 0; k < 128; ++k) a3 = fmaf(s2[k], Wc3[k * 2 + t], a3);
        out[b * 2 + t] = a3;
    }
}

extern "C" void kernel_launch(void* const* d_in, const int* in_sizes, int n_in,
                              void* d_out, int out_size, void* d_ws, size_t ws_size,
                              hipStream_t stream) {
    const float* x = (const float*)d_in[0];
    const int* ei = (const int*)d_in[1];
    const float* ew = (const float*)d_in[2];
    const int* batch = (const int*)d_in[3];
    const float* gf = (const float*)d_in[4];
    const float* W_in = (const float*)d_in[5];
    const float* b_in = (const float*)d_in[6];
    const float* ln_in_g = (const float*)d_in[7];
    const float* ln_in_b = (const float*)d_in[8];
    const float* eps = (const float*)d_in[9];
    const float* W1 = (const float*)d_in[10];
    const float* b1 = (const float*)d_in[11];
    const float* W2 = (const float*)d_in[12];
    const float* b2 = (const float*)d_in[13];
    const float* ln_g = (const float*)d_in[14];
    const float* ln_b = (const float*)d_in[15];
    const float* Wg1 = (const float*)d_in[16];
    const float* bg1 = (const float*)d_in[17];
    const float* lng_g = (const float*)d_in[18];
    const float* lng_b = (const float*)d_in[19];
    const float* Wg2 = (const float*)d_in[20];
    const float* bg2 = (const float*)d_in[21];
    const float* Wc1 = (const float*)d_in[22];
    const float* bc1 = (const float*)d_in[23];
    const float* Wc2 = (const float*)d_in[24];
    const float* bc2 = (const float*)d_in[25];
    const float* Wc3 = (const float*)d_in[26];
    const float* bc3 = (const float*)d_in[27];
    float* out = (float*)d_out;

    char* ws = (char*)d_ws;
    size_t off = 0;
    auto alloc = [&](size_t bytes) -> char* {
        char* p = ws + off;
        off += (bytes + 255) & ~(size_t)255;
        return p;
    };
    u16* Hh0 = (u16*)alloc((size_t)MP * H_DIM * 2);
    u16* Hl0 = (u16*)alloc((size_t)MP * H_DIM * 2);
    u16* Hh1 = (u16*)alloc((size_t)MP * H_DIM * 2);
    u16* Hl1 = (u16*)alloc((size_t)MP * H_DIM * 2);
    u16* Ah = (u16*)alloc((size_t)MP * H_DIM * 2);
    u16* Al = (u16*)alloc((size_t)MP * H_DIM * 2);
    u16* C1h = (u16*)alloc((size_t)MP * H2_DIM * 2);
    u16* C1l = (u16*)alloc((size_t)MP * H2_DIM * 2);
    u16* W1T = (u16*)alloc((size_t)4 * H2_DIM * H_DIM * 2);
    u16* W2T = (u16*)alloc((size_t)4 * H_DIM * H2_DIM * 2);
    int* deg = (int*)alloc(N_NODES * 4);
    int* cursor = (int*)alloc(N_NODES * 4);
    int* row_start = (int*)alloc((N_NODES + 1) * 4);
    int* bsum = (int*)alloc(256 * 4);
    int* gcnt = (int*)alloc(N_B * 4);
    int* gstart = (int*)alloc(N_B * 4);
    int* csr_src = (int*)alloc(N_EDGES * 4);
    float* csr_w = (float*)alloc(N_EDGES * 4);
    float* gbuf = (float*)alloc(N_B * 640 * 4);
    (void)ws_size; (void)in_sizes; (void)n_in; (void)out_size;

    // zero deg + cursor — span computed from pointers so padding is covered
    hipMemsetAsync(deg, 0, (size_t)((char*)row_start - (char*)deg), stream);

    // weight transpose -> fp16 (coalesced LDS-tile transpose)
    k_wprep<<<dim3(H2_DIM / 64, H_DIM / 64, 4), 256, 0, stream>>>(W1, W1T, H_DIM, H2_DIM);
    k_wprep<<<dim3(H_DIM / 64, H2_DIM / 64, 4), 256, 0, stream>>>(W2, W2T, H2_DIM, H_DIM);

    k_input_proj<<<N_NODES, 256, 0, stream>>>(x, W_in, b_in, ln_in_g, ln_in_b, Hh0, Hl0);
    k_hist<<<N_EDGES / 256, 256, 0, stream>>>(ei, deg);
    k_scan1<<<SCAN_NBLK, 256, 0, stream>>>(deg, row_start, bsum);
    k_scan2<<<1, 256, 0, stream>>>(bsum);
    k_scan3<<<SCAN_NBLK, 256, 0, stream>>>(row_start, bsum);
    k_scatter<<<N_EDGES / 256, 256, 0, stream>>>(ei, ew, row_start, cursor, csr_src, csr_w);
    k_gbounds<<<1, N_B, 0, stream>>>(batch, gstart, gcnt);

    u16* hch = Hh0; u16* hcl = Hl0;
    u16* hnh = Hh1; u16* hnl = Hl1;
    for (int l = 0; l < 4; ++l) {
        k_agg<<<N_NODES, 256, 0, stream>>>(hch, hcl, row_start, csr_src, csr_w, eps, l, Ah, Al);
        k_mgemm1<<<dim3(MP / 128, 4), 256, 0, stream>>>(
            Ah, Al, W1T + (size_t)l * H2_DIM * H_DIM,
            b1 + (size_t)l * H2_DIM, C1h, C1l);
        k_mgemm2<<<MP / 64, 256, 0, stream>>>(
            C1h, C1l, W2T + (size_t)l * H_DIM * H2_DIM,
            b2 + (size_t)l * H_DIM, ln_g + (size_t)l * H_DIM, ln_b + (size_t)l * H_DIM,
            hch, hcl, hnh, hnl);
        u16* th = hch; hch = hnh; hnh = th;
        u16* tl = hcl; hcl = hnl; hnl = tl;
    }

    k_pool<<<dim3(N_B, 4), 256, 0, stream>>>(hch, hcl, gstart, gcnt, gbuf);
    k_gene<<<N_B, 256, 0, stream>>>(gf, Wg1, bg1, lng_g, lng_b, Wg2, bg2, gbuf);
    k_cls<<<N_B, 256, 0, stream>>>(gbuf, Wc1, bc1, Wc2, bc2, Wc3, bc3, out);
}

// Round 6
// 849.014 us; speedup vs baseline: 2.7779x; 1.2775x over previous
//
#include <hip/hip_runtime.h>
#include <hip/hip_bf16.h>

#define N_NODES 50000
#define MP 50048            // padded row count (multiple of 128)
#define N_EDGES 800000
#define N_B 128
#define H_DIM 256
#define H2_DIM 512
#define FIN_DIM 8
#define GF_DIM 85
#define LN_EPS 1e-5f
#define SCAN_NBLK 196       // ceil(50000/256)

typedef unsigned short u16;
typedef unsigned int u32;
typedef _Float16 f16;
typedef __attribute__((ext_vector_type(8))) _Float16 f16x8;
typedef __attribute__((ext_vector_type(4))) float f32x4;

__device__ inline float relu_f(float x) { return x > 0.f ? x : 0.f; }

__device__ inline float h2f(u16 b) { f16 h; __builtin_memcpy(&h, &b, 2); return (float)h; }
__device__ inline u16 f2h(float x) { f16 h = (f16)x; u16 b; __builtin_memcpy(&b, &h, 2); return b; }

#define GLOAD16(gp, lp) __builtin_amdgcn_global_load_lds( \
    (const __attribute__((address_space(1))) void*)(gp),  \
    (__attribute__((address_space(3))) void*)(lp), 16, 0, 0)

// LayerNorm stats across a 256-thread block (one value per thread)
__device__ inline void ln_stats_256(float v, float* sbuf, float& mean, float& rstd) {
    float s = v, s2 = v * v;
#pragma unroll
    for (int off = 32; off > 0; off >>= 1) {
        s += __shfl_down(s, off);
        s2 += __shfl_down(s2, off);
    }
    int t = threadIdx.x;
    if ((t & 63) == 0) { sbuf[t >> 6] = s; sbuf[4 + (t >> 6)] = s2; }
    __syncthreads();
    float ts = sbuf[0] + sbuf[1] + sbuf[2] + sbuf[3];
    float ts2 = sbuf[4] + sbuf[5] + sbuf[6] + sbuf[7];
    mean = ts * (1.f / H_DIM);
    float var = ts2 * (1.f / H_DIM) - mean * mean;
    rstd = rsqrtf(var + LN_EPS);
}

// --- input projection: h = relu(LN(x @ W_in + b_in)), split-fp16 out ---------
__global__ void k_input_proj(const float* __restrict__ x, const float* __restrict__ Wi,
                             const float* __restrict__ bi, const float* __restrict__ g,
                             const float* __restrict__ bb,
                             u16* __restrict__ Hh, u16* __restrict__ Hl) {
    int n = blockIdx.x, t = threadIdx.x;
    __shared__ float xs[FIN_DIM];
    __shared__ float sbuf[8];
    if (t < FIN_DIM) xs[t] = x[n * FIN_DIM + t];
    __syncthreads();
    float acc = bi[t];
#pragma unroll
    for (int k = 0; k < FIN_DIM; ++k) acc = fmaf(xs[k], Wi[k * H_DIM + t], acc);
    float mean, rstd;
    ln_stats_256(acc, sbuf, mean, rstd);
    float v = relu_f(g[t] * (acc - mean) * rstd + bb[t]);
    u16 hh = f2h(v);
    size_t o = (size_t)n * H_DIM + t;
    Hh[o] = hh;
    Hl[o] = f2h(v - h2f(hh));
}

// ---------------- CSR build ---------------------------------------------------
__global__ void k_hist(const int* __restrict__ ei, int* __restrict__ deg) {
    int e = blockIdx.x * 256 + threadIdx.x;
    atomicAdd(&deg[ei[N_EDGES + e]], 1);
}

// 3-stage parallel exclusive scan of deg -> row_start
__global__ void k_scan1(const int* __restrict__ deg, int* __restrict__ row_start,
                        int* __restrict__ bsum) {
    __shared__ int s[256];
    int t = threadIdx.x, i = blockIdx.x * 256 + t;
    int v = (i < N_NODES) ? deg[i] : 0;
    s[t] = v;
    __syncthreads();
    for (int off = 1; off < 256; off <<= 1) {
        int x = (t >= off) ? s[t - off] : 0;
        __syncthreads();
        s[t] += x;
        __syncthreads();
    }
    if (i < N_NODES) row_start[i] = s[t] - v;  // exclusive within block
    if (t == 255) bsum[blockIdx.x] = s[255];
}

__global__ void k_scan2(int* __restrict__ bsum) {
    __shared__ int s[256];
    int t = threadIdx.x;
    int v = (t < SCAN_NBLK) ? bsum[t] : 0;
    s[t] = v;
    __syncthreads();
    for (int off = 1; off < 256; off <<= 1) {
        int x = (t >= off) ? s[t - off] : 0;
        __syncthreads();
        s[t] += x;
        __syncthreads();
    }
    if (t < SCAN_NBLK) bsum[t] = s[t] - v;  // exclusive block offsets
}

__global__ void k_scan3(int* __restrict__ row_start, const int* __restrict__ bsum) {
    int t = threadIdx.x, i = blockIdx.x * 256 + t;
    if (i < N_NODES) row_start[i] += bsum[blockIdx.x];
    if (i == 0) row_start[N_NODES] = N_EDGES;
}

__global__ void k_scatter(const int* __restrict__ ei, const float* __restrict__ ew,
                          const int* __restrict__ row_start, int* __restrict__ cursor,
                          int* __restrict__ csr_src, float* __restrict__ csr_w) {
    int e = blockIdx.x * 256 + threadIdx.x;
    int d = ei[N_EDGES + e];
    int p = atomicAdd(&cursor[d], 1);
    int i = row_start[d] + p;
    csr_src[i] = ei[e];
    csr_w[i] = ew[e];
}

// batch is sorted: graph b occupies [gstart[b], gstart[b+1])  — binary search
__global__ void k_gbounds(const int* __restrict__ batch, int* __restrict__ gstart,
                          int* __restrict__ gcnt) {
    __shared__ int s[N_B + 1];
    int b = threadIdx.x;  // 0..127
    int lo = 0, hi = N_NODES;
    while (lo < hi) {
        int mid = (lo + hi) >> 1;
        if (batch[mid] < b) lo = mid + 1; else hi = mid;
    }
    s[b] = lo;
    if (b == 0) s[N_B] = N_NODES;
    __syncthreads();
    gstart[b] = s[b];
    gcnt[b] = s[b + 1] - s[b];
}

// ---- GIN aggregation: A = fp16( (2+eps)*h + sum_in w*Hh[src] ) ---------------
// wave-per-edge: each wave loads a full 512B row (8 B/lane), 4-wave LDS combine
__global__ void k_agg(const u16* __restrict__ Hh, const u16* __restrict__ Hl,
                      const int* __restrict__ row_start,
                      const int* __restrict__ csr_src, const float* __restrict__ csr_w,
                      const float* __restrict__ eps, int layer,
                      u16* __restrict__ Ah) {
    const int n = blockIdx.x, t = threadIdx.x, wv = t >> 6, lane = t & 63;
    __shared__ int s_src[256];
    __shared__ float s_w[256];
    __shared__ float part[4][256];
    int start = row_start[n], end = row_start[n + 1];
    float a0 = 0.f, a1 = 0.f, a2 = 0.f, a3 = 0.f;
    for (int e0 = start; e0 < end; e0 += 256) {
        int ne = end - e0; if (ne > 256) ne = 256;
        if (t < ne) { s_src[t] = csr_src[e0 + t]; s_w[t] = csr_w[e0 + t]; }
        __syncthreads();
        for (int j = wv; j < ne; j += 4) {
            int src = s_src[j];
            float w = s_w[j];
            ushort4 v = *reinterpret_cast<const ushort4*>(&Hh[(size_t)src * H_DIM + lane * 4]);
            a0 = fmaf(w, h2f(v.x), a0);
            a1 = fmaf(w, h2f(v.y), a1);
            a2 = fmaf(w, h2f(v.z), a2);
            a3 = fmaf(w, h2f(v.w), a3);
        }
        __syncthreads();
    }
    *reinterpret_cast<float4*>(&part[wv][lane * 4]) = (float4){a0, a1, a2, a3};
    __syncthreads();
    float sum = part[0][t] + part[1][t] + part[2][t] + part[3][t];
    size_t so = (size_t)n * H_DIM + t;
    float e2 = 2.0f + eps[layer];
    float hs = h2f(Hh[so]) + h2f(Hl[so]);
    Ah[so] = f2h(e2 * hs + sum);
}

// ---- weight transpose -> fp16: T[l][c][r] = f16(W[l][r][c]), coalesced -------
__global__ void k_wprep(const float* __restrict__ W, u16* __restrict__ T, int R, int C) {
    __shared__ float tile[64][65];
    int c0 = blockIdx.x * 64, r0 = blockIdx.y * 64;
    const float* Wl = W + (size_t)blockIdx.z * R * C;
    u16* Tl_ = T + (size_t)blockIdx.z * R * C;
    int t = threadIdx.x;
    int col = t & 63, qr = t >> 6;
#pragma unroll
    for (int i = 0; i < 16; ++i) {
        int row = i * 4 + qr;
        tile[row][col] = Wl[(size_t)(r0 + row) * C + c0 + col];
    }
    __syncthreads();
#pragma unroll
    for (int i = 0; i < 16; ++i) {
        int crow = i * 4 + qr;  // transposed row = original col
        Tl_[(size_t)(c0 + crow) * R + r0 + col] = f2h(tile[col][crow]);
    }
}

// ---- MFMA GEMM1: C1 = relu(A[MP,256] @ W1[256,512] + b), fp16 io -------------
// A fp16 [MP][256]; W1T fp16 [512][256]; out C1 fp16 [MP][512]
__global__ __launch_bounds__(256, 2) void k_mgemm1(
    const u16* __restrict__ Ah, const u16* __restrict__ Wt,
    const float* __restrict__ bias, u16* __restrict__ Ch) {
    __shared__ __align__(16) u16 sA[128 * 32];
    __shared__ __align__(16) u16 sB[128 * 32];
    const int t = threadIdx.x;
    const int wv = t >> 6, lane = t & 63;
    const int fr = lane & 15, kg = lane >> 4;
    const int m0 = blockIdx.x * 128, n0 = blockIdx.y * 128;
    const int wm = (wv >> 1) * 64, wn = (wv & 1) * 64;

    f32x4 acc[4][4];
#pragma unroll
    for (int i = 0; i < 4; ++i)
#pragma unroll
        for (int j = 0; j < 4; ++j) acc[i][j] = (f32x4){0.f, 0.f, 0.f, 0.f};

    for (int k0 = 0; k0 < 256; k0 += 32) {
#pragma unroll
        for (int is = 0; is < 2; ++is) {
            int chunk = wv * 128 + is * 64 + lane;
            int r = chunk >> 2, p = chunk & 3;
            size_t ea = (size_t)(m0 + r) * 256 + k0 + p * 8;
            size_t eb = (size_t)(n0 + r) * 256 + k0 + p * 8;
            int lbase = (wv * 128 + is * 64) * 8;
            GLOAD16(Ah + ea, &sA[lbase]);
            GLOAD16(Wt + eb, &sB[lbase]);
        }
        __syncthreads();
        f16x8 fa[4], fb[4];
#pragma unroll
        for (int mf = 0; mf < 4; ++mf) {
            int off = (wm + mf * 16 + fr) * 32 + kg * 8;
            fa[mf] = *(const f16x8*)&sA[off];
        }
#pragma unroll
        for (int nf = 0; nf < 4; ++nf) {
            int off = (wn + nf * 16 + fr) * 32 + kg * 8;
            fb[nf] = *(const f16x8*)&sB[off];
        }
#pragma unroll
        for (int mf = 0; mf < 4; ++mf)
#pragma unroll
            for (int nf = 0; nf < 4; ++nf)
                acc[mf][nf] = __builtin_amdgcn_mfma_f32_16x16x32_f16(fa[mf], fb[nf], acc[mf][nf], 0, 0, 0);
        __syncthreads();
    }
#pragma unroll
    for (int nf = 0; nf < 4; ++nf) {
        int col = n0 + wn + nf * 16 + fr;
        float bi = bias[col];
#pragma unroll
        for (int mf = 0; mf < 4; ++mf)
#pragma unroll
            for (int j = 0; j < 4; ++j) {
                int grow = m0 + wm + mf * 16 + kg * 4 + j;
                Ch[(size_t)grow * 512 + col] = f2h(relu_f(acc[mf][nf][j] + bi));
            }
    }
}

// -- MFMA GEMM2 + LN + relu + residual: hout = relu(LN(C1@W2+b2)) + hres -------
__global__ __launch_bounds__(256, 2) void k_mgemm2(
    const u16* __restrict__ Ah, const u16* __restrict__ Wt,
    const float* __restrict__ bias, const float* __restrict__ lg,
    const float* __restrict__ lbv,
    const u16* __restrict__ Rh, const u16* __restrict__ Rl,
    u16* __restrict__ Oh, u16* __restrict__ Ol) {
    __shared__ __align__(16) u16 sA[64 * 32];
    __shared__ __align__(16) u16 sB[256 * 32];
    __shared__ float lnS[64][4], lnS2[64][4];
    __shared__ float lnm[64], lnr[64];
    const int t = threadIdx.x;
    const int wv = t >> 6, lane = t & 63;
    const int fr = lane & 15, kg = lane >> 4;
    const int m0 = blockIdx.x * 64;

    f32x4 acc[4][4];
#pragma unroll
    for (int i = 0; i < 4; ++i)
#pragma unroll
        for (int j = 0; j < 4; ++j) acc[i][j] = (f32x4){0.f, 0.f, 0.f, 0.f};

    for (int k0 = 0; k0 < 512; k0 += 32) {
        {
            int r = t >> 2, p = t & 3;
            size_t ea = (size_t)(m0 + r) * 512 + k0 + p * 8;
            int lbase = (wv * 64) * 8;
            GLOAD16(Ah + ea, &sA[lbase]);
        }
#pragma unroll
        for (int is = 0; is < 4; ++is) {
            int chunk = is * 256 + t;
            int r = chunk >> 2, p = chunk & 3;
            size_t eb = (size_t)r * 512 + k0 + p * 8;
            int lbase = (is * 256 + wv * 64) * 8;
            GLOAD16(Wt + eb, &sB[lbase]);
        }
        __syncthreads();
        f16x8 fa[4], fb[4];
#pragma unroll
        for (int mf = 0; mf < 4; ++mf) {
            int off = (mf * 16 + fr) * 32 + kg * 8;
            fa[mf] = *(const f16x8*)&sA[off];
        }
#pragma unroll
        for (int nf = 0; nf < 4; ++nf) {
            int off = (wv * 64 + nf * 16 + fr) * 32 + kg * 8;
            fb[nf] = *(const f16x8*)&sB[off];
        }
#pragma unroll
        for (int mf = 0; mf < 4; ++mf)
#pragma unroll
            for (int nf = 0; nf < 4; ++nf)
                acc[mf][nf] = __builtin_amdgcn_mfma_f32_16x16x32_f16(fa[mf], fb[nf], acc[mf][nf], 0, 0, 0);
        __syncthreads();
    }
    float bcol[4];
#pragma unroll
    for (int nf = 0; nf < 4; ++nf) bcol[nf] = bias[wv * 64 + nf * 16 + fr];
#pragma unroll
    for (int mf = 0; mf < 4; ++mf)
#pragma unroll
        for (int nf = 0; nf < 4; ++nf)
#pragma unroll
            for (int j = 0; j < 4; ++j) acc[mf][nf][j] += bcol[nf];
#pragma unroll
    for (int mf = 0; mf < 4; ++mf)
#pragma unroll
        for (int j = 0; j < 4; ++j) {
            float s = acc[mf][0][j] + acc[mf][1][j] + acc[mf][2][j] + acc[mf][3][j];
            float s2 = acc[mf][0][j] * acc[mf][0][j] + acc[mf][1][j] * acc[mf][1][j] +
                       acc[mf][2][j] * acc[mf][2][j] + acc[mf][3][j] * acc[mf][3][j];
#pragma unroll
            for (int off = 1; off < 16; off <<= 1) {
                s += __shfl_xor(s, off);
                s2 += __shfl_xor(s2, off);
            }
            if (fr == 0) {
                int row = mf * 16 + kg * 4 + j;
                lnS[row][wv] = s;
                lnS2[row][wv] = s2;
            }
        }
    __syncthreads();
    if (t < 64) {
        float s = lnS[t][0] + lnS[t][1] + lnS[t][2] + lnS[t][3];
        float s2 = lnS2[t][0] + lnS2[t][1] + lnS2[t][2] + lnS2[t][3];
        float m = s * (1.f / 256.f);
        float var = s2 * (1.f / 256.f) - m * m;
        lnm[t] = m;
        lnr[t] = rsqrtf(var + LN_EPS);
    }
    __syncthreads();
    float gg[4], bb[4];
#pragma unroll
    for (int nf = 0; nf < 4; ++nf) {
        int col = wv * 64 + nf * 16 + fr;
        gg[nf] = lg[col];
        bb[nf] = lbv[col];
    }
#pragma unroll
    for (int mf = 0; mf < 4; ++mf)
#pragma unroll
        for (int j = 0; j < 4; ++j) {
            int row = mf * 16 + kg * 4 + j;
            int grow = m0 + row;
            float m = lnm[row], rs = lnr[row];
#pragma unroll
            for (int nf = 0; nf < 4; ++nf) {
                int col = wv * 64 + nf * 16 + fr;
                size_t o = (size_t)grow * 256 + col;
                float res = h2f(Rh[o]) + h2f(Rl[o]);
                float v = relu_f(gg[nf] * (acc[mf][nf][j] - m) * rs + bb[nf]) + res;
                u16 hh = f2h(v);
                Oh[o] = hh;
                Ol[o] = f2h(v - h2f(hh));
            }
        }
}

// -------- pooling (mean + max per graph), 4 col-chunks x 4-way rows -----------
__global__ void k_pool(const u16* __restrict__ Hh, const u16* __restrict__ Hl,
                       const int* __restrict__ gstart,
                       const int* __restrict__ gcnt, float* __restrict__ g) {
    int b = blockIdx.x;
    int col = blockIdx.y * 64 + (threadIdx.x & 63);
    int r = threadIdx.x >> 6;
    int st = gstart[b], cnt = gcnt[b];
    float s = 0.f, mx = -3.4e38f;
    for (int i = r; i < cnt; i += 4) {
        size_t o = (size_t)(st + i) * H_DIM + col;
        float v = h2f(Hh[o]) + h2f(Hl[o]);
        s += v;
        mx = fmaxf(mx, v);
    }
    __shared__ float ss[256], sm[256];
    ss[threadIdx.x] = s;
    sm[threadIdx.x] = mx;
    __syncthreads();
    if (r == 0) {
#pragma unroll
        for (int k = 1; k < 4; ++k) {
            s += ss[threadIdx.x + 64 * k];
            mx = fmaxf(mx, sm[threadIdx.x + 64 * k]);
        }
        float mean = cnt > 0 ? s / (float)cnt : 0.f;
        if (cnt == 0) mx = 0.f;
        g[b * 640 + col] = mean;
        g[b * 640 + 256 + col] = mx;
    }
}

// ---------------- gene projection --------------------------------------------
__global__ void k_gene(const float* __restrict__ gf, const float* __restrict__ Wg1,
                       const float* __restrict__ bg1, const float* __restrict__ lg,
                       const float* __restrict__ lb, const float* __restrict__ Wg2,
                       const float* __restrict__ bg2, float* __restrict__ g) {
    int b = blockIdx.x, t = threadIdx.x;
    __shared__ float xs[GF_DIM];
    __shared__ float sbuf[8];
    __shared__ float s1[H_DIM];
    if (t < GF_DIM) xs[t] = gf[b * GF_DIM + t];
    __syncthreads();
    float acc = bg1[t];
    for (int k = 0; k < GF_DIM; ++k) acc = fmaf(xs[k], Wg1[k * H_DIM + t], acc);
    float mean, rstd;
    ln_stats_256(acc, sbuf, mean, rstd);
    s1[t] = relu_f(lg[t] * (acc - mean) * rstd + lb[t]);
    __syncthreads();
    if (t < 128) {
        float a2 = bg2[t];
        for (int k = 0; k < H_DIM; ++k) a2 = fmaf(s1[k], Wg2[k * 128 + t], a2);
        g[b * 640 + 512 + t] = relu_f(a2);
    }
}

// ---------------- classifier --------------------------------------------------
__global__ void k_cls(const float* __restrict__ g, const float* __restrict__ Wc1,
                      const float* __restrict__ bc1, const float* __restrict__ Wc2,
                      const float* __restrict__ bc2, const float* __restrict__ Wc3,
                      const float* __restrict__ bc3, float* __restrict__ out) {
    int b = blockIdx.x, t = threadIdx.x;
    __shared__ float gg[640];
    __shared__ float s1[256];
    __shared__ float s2[128];
    gg[t] = g[b * 640 + t];
    gg[t + 256] = g[b * 640 + 256 + t];
    if (t < 128) gg[t + 512] = g[b * 640 + 512 + t];
    __syncthreads();
    float a = bc1[t];
    for (int k = 0; k < 640; ++k) a = fmaf(gg[k], Wc1[k * 256 + t], a);
    s1[t] = relu_f(a);
    __syncthreads();
    if (t < 128) {
        float a2 = bc2[t];
        for (int k = 0; k < 256; ++k) a2 = fmaf(s1[k], Wc2[k * 128 + t], a2);
        s2[t] = relu_f(a2);
    }
    __syncthreads();
    if (t < 2) {
        float a3 = bc3[t];
        for (int k = 0; k < 128; ++k) a3 = fmaf(s2[k], Wc3[k * 2 + t], a3);
        out[b * 2 + t] = a3;
    }
}

extern "C" void kernel_launch(void* const* d_in, const int* in_sizes, int n_in,
                              void* d_out, int out_size, void* d_ws, size_t ws_size,
                              hipStream_t stream) {
    const float* x = (const float*)d_in[0];
    const int* ei = (const int*)d_in[1];
    const float* ew = (const float*)d_in[2];
    const int* batch = (const int*)d_in[3];
    const float* gf = (const float*)d_in[4];
    const float* W_in = (const float*)d_in[5];
    const float* b_in = (const float*)d_in[6];
    const float* ln_in_g = (const float*)d_in[7];
    const float* ln_in_b = (const float*)d_in[8];
    const float* eps = (const float*)d_in[9];
    const float* W1 = (const float*)d_in[10];
    const float* b1 = (const float*)d_in[11];
    const float* W2 = (const float*)d_in[12];
    const float* b2 = (const float*)d_in[13];
    const float* ln_g = (const float*)d_in[14];
    const float* ln_b = (const float*)d_in[15];
    const float* Wg1 = (const float*)d_in[16];
    const float* bg1 = (const float*)d_in[17];
    const float* lng_g = (const float*)d_in[18];
    const float* lng_b = (const float*)d_in[19];
    const float* Wg2 = (const float*)d_in[20];
    const float* bg2 = (const float*)d_in[21];
    const float* Wc1 = (const float*)d_in[22];
    const float* bc1 = (const float*)d_in[23];
    const float* Wc2 = (const float*)d_in[24];
    const float* bc2 = (const float*)d_in[25];
    const float* Wc3 = (const float*)d_in[26];
    const float* bc3 = (const float*)d_in[27];
    float* out = (float*)d_out;

    char* ws = (char*)d_ws;
    size_t off = 0;
    auto alloc = [&](size_t bytes) -> char* {
        char* p = ws + off;
        off += (bytes + 255) & ~(size_t)255;
        return p;
    };
    u16* Hh0 = (u16*)alloc((size_t)MP * H_DIM * 2);
    u16* Hl0 = (u16*)alloc((size_t)MP * H_DIM * 2);
    u16* Hh1 = (u16*)alloc((size_t)MP * H_DIM * 2);
    u16* Hl1 = (u16*)alloc((size_t)MP * H_DIM * 2);
    u16* Ah = (u16*)alloc((size_t)MP * H_DIM * 2);
    u16* C1h = (u16*)alloc((size_t)MP * H2_DIM * 2);
    u16* W1T = (u16*)alloc((size_t)4 * H2_DIM * H_DIM * 2);
    u16* W2T = (u16*)alloc((size_t)4 * H_DIM * H2_DIM * 2);
    int* deg = (int*)alloc(N_NODES * 4);
    int* cursor = (int*)alloc(N_NODES * 4);
    int* row_start = (int*)alloc((N_NODES + 1) * 4);
    int* bsum = (int*)alloc(256 * 4);
    int* gcnt = (int*)alloc(N_B * 4);
    int* gstart = (int*)alloc(N_B * 4);
    int* csr_src = (int*)alloc(N_EDGES * 4);
    float* csr_w = (float*)alloc(N_EDGES * 4);
    float* gbuf = (float*)alloc(N_B * 640 * 4);
    (void)ws_size; (void)in_sizes; (void)n_in; (void)out_size;

    // zero deg + cursor — span computed from pointers so padding is covered
    hipMemsetAsync(deg, 0, (size_t)((char*)row_start - (char*)deg), stream);

    // weight transpose -> fp16 (coalesced LDS-tile transpose)
    k_wprep<<<dim3(H2_DIM / 64, H_DIM / 64, 4), 256, 0, stream>>>(W1, W1T, H_DIM, H2_DIM);
    k_wprep<<<dim3(H_DIM / 64, H2_DIM / 64, 4), 256, 0, stream>>>(W2, W2T, H2_DIM, H_DIM);

    k_input_proj<<<N_NODES, 256, 0, stream>>>(x, W_in, b_in, ln_in_g, ln_in_b, Hh0, Hl0);
    k_hist<<<N_EDGES / 256, 256, 0, stream>>>(ei, deg);
    k_scan1<<<SCAN_NBLK, 256, 0, stream>>>(deg, row_start, bsum);
    k_scan2<<<1, 256, 0, stream>>>(bsum);
    k_scan3<<<SCAN_NBLK, 256, 0, stream>>>(row_start, bsum);
    k_scatter<<<N_EDGES / 256, 256, 0, stream>>>(ei, ew, row_start, cursor, csr_src, csr_w);
    k_gbounds<<<1, N_B, 0, stream>>>(batch, gstart, gcnt);

    u16* hch = Hh0; u16* hcl = Hl0;
    u16* hnh = Hh1; u16* hnl = Hl1;
    for (int l = 0; l < 4; ++l) {
        k_agg<<<N_NODES, 256, 0, stream>>>(hch, hcl, row_start, csr_src, csr_w, eps, l, Ah);
        k_mgemm1<<<dim3(MP / 128, 4), 256, 0, stream>>>(
            Ah, W1T + (size_t)l * H2_DIM * H_DIM,
            b1 + (size_t)l * H2_DIM, C1h);
        k_mgemm2<<<MP / 64, 256, 0, stream>>>(
            C1h, W2T + (size_t)l * H_DIM * H2_DIM,
            b2 + (size_t)l * H_DIM, ln_g + (size_t)l * H_DIM, ln_b + (size_t)l * H_DIM,
            hch, hcl, hnh, hnl);
        u16* th = hch; hch = hnh; hnh = th;
        u16* tl = hcl; hcl = hnl; hnl = tl;
    }

    k_pool<<<dim3(N_B, 4), 256, 0, stream>>>(hch, hcl, gstart, gcnt, gbuf);
    k_gene<<<N_B, 256, 0, stream>>>(gf, Wg1, bg1, lng_g, lng_b, Wg2, bg2, gbuf);
    k_cls<<<N_B, 256, 0, stream>>>(gbuf, Wc1, bc1, Wc2, bc2, Wc3, bc3, out);
}